// Round 1
// 1104.195 us; speedup vs baseline: 1.2968x; 1.2968x over previous
//
#include <hip/hip_runtime.h>

#define B_    2
#define S_    2048
#define D_    4096
#define NH_   32
#define NKV_  8
#define HD_   128
#define M_TOK 4096           // B_*S_
#define NQKV  6144           // (NH_+2*NKV_)*HD_
#define SCALE 0.08838834764831845f

typedef unsigned short u16;
typedef unsigned int   u32;
typedef __attribute__((ext_vector_type(8))) short short8;
typedef __attribute__((ext_vector_type(4))) float floatx4;
typedef __attribute__((ext_vector_type(16))) float floatx16;

__device__ inline u16 f2bf(float f) {
    u32 u = __float_as_uint(f);
    u = (u + 0x7FFFu + ((u >> 16) & 1u)) >> 16;
    return (u16)u;
}
__device__ inline float bf2f(u16 u) {
    return __uint_as_float(((u32)u) << 16);
}

// ---------------------------------------------------------------------------
// B^T GEMM (unchanged): C[m,n] = sum_k A[m,k] * W[n,k].
// ---------------------------------------------------------------------------
template<bool A_BF16, bool OUT_F32>
__global__ __launch_bounds__(256) void gemm_bt(
    const void* __restrict__ Ap,
    const float* __restrict__ B0, const float* __restrict__ B1,
    const float* __restrict__ B2, int nb0, int nb1,
    void* __restrict__ Cp, int M, int N, int K)
{
    __shared__ __align__(16) u16 As[128][40];
    __shared__ __align__(16) u16 Bs[128][40];

    const int tid  = threadIdx.x;
    const int lane = tid & 63, wave = tid >> 6;
    const int quad = lane >> 4, l16 = lane & 15;
    const int m0 = blockIdx.y * 128, n0 = blockIdx.x * 128;
    const int wm = (wave >> 1) * 64, wn = (wave & 1) * 64;

    floatx4 acc[4][4];
    #pragma unroll
    for (int i = 0; i < 4; ++i)
        #pragma unroll
        for (int j = 0; j < 4; ++j) acc[i][j] = (floatx4){0.f, 0.f, 0.f, 0.f};

    for (int k0 = 0; k0 < K; k0 += 32) {
        if constexpr (!A_BF16) {
            const float* A = (const float*)Ap;
            int row = tid >> 3, cg = tid & 7;
            #pragma unroll
            for (int it = 0; it < 4; ++it, row += 32) {
                float4 v = *(const float4*)(A + (size_t)(m0 + row) * K + k0 + cg * 4);
                u32 p01 = (u32)f2bf(v.x) | ((u32)f2bf(v.y) << 16);
                u32 p23 = (u32)f2bf(v.z) | ((u32)f2bf(v.w) << 16);
                *(uint2*)&As[row][cg * 4] = make_uint2(p01, p23);
            }
        } else {
            const u16* A = (const u16*)Ap;
            int row = tid >> 2, cg = tid & 3;
            #pragma unroll
            for (int it = 0; it < 2; ++it, row += 64) {
                *(short8*)&As[row][cg * 8] =
                    *(const short8*)(A + (size_t)(m0 + row) * K + k0 + cg * 8);
            }
        }
        {
            int row = tid >> 3, cg = tid & 7;
            #pragma unroll
            for (int it = 0; it < 4; ++it, row += 32) {
                int rr = n0 + row;
                const float* src;
                if (rr < nb0)      src = B0 + (size_t)rr * K;
                else if (rr < nb1) src = B1 + (size_t)(rr - nb0) * K;
                else               src = B2 + (size_t)(rr - nb1) * K;
                float4 v = *(const float4*)(src + k0 + cg * 4);
                u32 p01 = (u32)f2bf(v.x) | ((u32)f2bf(v.y) << 16);
                u32 p23 = (u32)f2bf(v.z) | ((u32)f2bf(v.w) << 16);
                *(uint2*)&Bs[row][cg * 4] = make_uint2(p01, p23);
            }
        }
        __syncthreads();

        short8 af[4], bfv[4];
        #pragma unroll
        for (int i = 0; i < 4; ++i)
            af[i] = *(const short8*)&As[wm + i * 16 + l16][quad * 8];
        #pragma unroll
        for (int j = 0; j < 4; ++j)
            bfv[j] = *(const short8*)&Bs[wn + j * 16 + l16][quad * 8];
        #pragma unroll
        for (int i = 0; i < 4; ++i)
            #pragma unroll
            for (int j = 0; j < 4; ++j)
                acc[i][j] = __builtin_amdgcn_mfma_f32_16x16x32_bf16(
                    af[i], bfv[j], acc[i][j], 0, 0, 0);
        __syncthreads();
    }

    #pragma unroll
    for (int i = 0; i < 4; ++i)
        #pragma unroll
        for (int j = 0; j < 4; ++j)
            #pragma unroll
            for (int r = 0; r < 4; ++r) {
                int row = m0 + wm + i * 16 + quad * 4 + r;
                int col = n0 + wn + j * 16 + l16;
                float v = acc[i][j][r];
                if constexpr (OUT_F32)
                    ((float*)Cp)[(size_t)row * N + col] = v;
                else
                    ((u16*)Cp)[(size_t)row * N + col] = f2bf(v);
            }
}

// ---------------------------------------------------------------------------
// RoPE + head-major reshape for Q and K (unchanged).
// ---------------------------------------------------------------------------
__global__ __launch_bounds__(256) void rope_reshape(
    const u16* __restrict__ qkv, const float* __restrict__ cosp,
    const float* __restrict__ sinp, u16* __restrict__ Q, u16* __restrict__ Kb)
{
    const size_t QN = (size_t)M_TOK * NH_ * 64;
    size_t id = (size_t)blockIdx.x * 256 + threadIdx.x;
    if (id < QN) {
        int j = id & 63; int h = (id >> 6) & (NH_ - 1); int tok = (int)(id >> 11);
        int b = tok >> 11, s = tok & (S_ - 1);
        float c  = cosp[(size_t)tok * HD_ + j];
        float sn = sinp[(size_t)tok * HD_ + j];
        float x1 = bf2f(qkv[(size_t)tok * NQKV + h * HD_ + j]);
        float x2 = bf2f(qkv[(size_t)tok * NQKV + h * HD_ + 64 + j]);
        size_t o = ((size_t)(b * NH_ + h) * S_ + s) * HD_ + j;
        Q[o]      = f2bf(x1 * c - x2 * sn);
        Q[o + 64] = f2bf(x2 * c + x1 * sn);
    } else {
        size_t kid = id - QN;
        int j = kid & 63; int h = (kid >> 6) & (NKV_ - 1); int tok = (int)(kid >> 9);
        int b = tok >> 11, s = tok & (S_ - 1);
        float c  = cosp[(size_t)tok * HD_ + j];
        float sn = sinp[(size_t)tok * HD_ + j];
        float x1 = bf2f(qkv[(size_t)tok * NQKV + 4096 + h * HD_ + j]);
        float x2 = bf2f(qkv[(size_t)tok * NQKV + 4096 + h * HD_ + 64 + j]);
        size_t o = ((size_t)(b * NKV_ + h) * S_ + s) * HD_ + j;
        Kb[o]      = f2bf(x1 * c - x2 * sn);
        Kb[o + 64] = f2bf(x2 * c + x1 * sn);
    }
}

// ---------------------------------------------------------------------------
// V transpose (unchanged): qkv V part -> Vt[b,hk,d,s]
// ---------------------------------------------------------------------------
__global__ __launch_bounds__(256) void v_transpose(
    const u16* __restrict__ qkv, u16* __restrict__ Vt)
{
    __shared__ __align__(16) u16 T[128][136];
    int bidx = blockIdx.x;
    int st = bidx & 15; int h = (bidx >> 4) & 7; int b = bidx >> 7;
    int s0 = st * 128;
    int tid = threadIdx.x;
    #pragma unroll
    for (int i = 0; i < 8; ++i) {
        int row = i * 16 + (tid >> 4); int cg = tid & 15;
        const u16* src = qkv + (size_t)(b * S_ + s0 + row) * NQKV + 5120 + h * HD_ + cg * 8;
        *(short8*)&T[row][cg * 8] = *(const short8*)src;
    }
    __syncthreads();
    #pragma unroll
    for (int i = 0; i < 8; ++i) {
        int d = i * 16 + (tid >> 4); int cg = tid & 15;
        __align__(16) u16 tmp[8];
        #pragma unroll
        for (int j = 0; j < 8; ++j) tmp[j] = T[cg * 8 + j][d];
        *(short8*)(Vt + ((size_t)(b * NKV_ + h) * HD_ + d) * S_ + s0 + cg * 8) =
            *(short8*)tmp;
    }
}

// ---------------------------------------------------------------------------
// Flash attention v3.  Changes vs v2:
//  * 32-row q-tile per wave, mfma_f32_32x32x16_bf16 (K/V traffic per
//    P-element halves; 16 MFMAs per softmax instead of per half the work)
//  * XCD-aligned mapping: hk = blockIdx&7 -> each XCD's L2 holds only its
//    own KV head (2 MB working set < 4 MB L2); was 16 MB thrash via L3
//  * zero LDS: S^T = mfma(K,Q) leaves P row-local; reduce = 15 fmax +
//    shfl_xor(32); P->PV fragment built with 8 packs + 4 shfl_xor + selects
//  * skip O-rescale when no lane's row-max grew (exact, T13 w/ THR=0)
//  * s_setprio(1) around MFMA clusters (T5)
//  * blocks dispatched longest-first (qb reversed) for tail balance
// ---------------------------------------------------------------------------
__global__ __launch_bounds__(256) void flash_attn(
    const u16* __restrict__ Q, const u16* __restrict__ Kb,
    const u16* __restrict__ Vt, u16* __restrict__ AO)
{
    const int tid  = threadIdx.x;
    const int wave = tid >> 6, lane = tid & 63;
    const int l31 = lane & 31, hi = lane >> 5;

    const int i    = blockIdx.x;
    const int xcd  = i & 7;           // blockIdx round-robins XCDs
    const int slot = i >> 3;
    const int g    = slot & 3;        // q-head within kv group
    const int qb   = 15 - ((slot >> 2) & 15);   // longest blocks first
    const int b    = slot >> 6;
    const int hk   = xcd;             // one kv head per XCD -> L2-resident
    const int h    = hk * 4 + g;
    const int qt   = qb * 4 + wave;   // 32-row q-tile index [0,64)
    const int q0   = qt * 32;
    const int qpos = q0 + l31;

    const u16* Kbase = Kb + (size_t)(b * NKV_ + hk) * S_ * HD_;
    const u16* Vbase = Vt + (size_t)(b * NKV_ + hk) * HD_ * S_;

    // Q fragments: B-operand, col=l31 (q row), k = c*16 + hi*8 + j
    const u16* Qp = Q + ((size_t)(b * NH_ + h) * S_ + q0 + l31) * HD_ + hi * 8;
    short8 qf[8];
    #pragma unroll
    for (int c = 0; c < 8; ++c) qf[c] = *(const short8*)(Qp + c * 16);

    float m = -1e30f, l = 0.f;
    floatx16 o[4];
    #pragma unroll
    for (int n = 0; n < 4; ++n)
        #pragma unroll
        for (int r = 0; r < 16; ++r) o[n][r] = 0.f;

    const u16* Kp = Kbase + (size_t)l31 * HD_ + hi * 8;   // A-op: row=l31(kv)
    const u16* Vp = Vbase + (size_t)l31 * S_ + hi * 8;    // A-op: row=l31(d)

    for (int t = 0; t <= qt; ++t) {
        const int kb = t * 32;
        const u16* Kt = Kp + (size_t)kb * HD_;

        // S^T[kv][q] via two independent accumulator chains
        floatx16 ca, cb;
        #pragma unroll
        for (int r = 0; r < 16; ++r) { ca[r] = 0.f; cb[r] = 0.f; }
        __builtin_amdgcn_s_setprio(1);
        #pragma unroll
        for (int c = 0; c < 8; c += 2) {
            ca = __builtin_amdgcn_mfma_f32_32x32x16_bf16(
                *(const short8*)(Kt + c * 16), qf[c], ca, 0, 0, 0);
            cb = __builtin_amdgcn_mfma_f32_32x32x16_bf16(
                *(const short8*)(Kt + (c + 1) * 16), qf[c + 1], cb, 0, 0, 0);
        }
        __builtin_amdgcn_s_setprio(0);

        float s[16];
        #pragma unroll
        for (int r = 0; r < 16; ++r) s[r] = ca[r] + cb[r];

        if (t == qt) {                 // diagonal tile: causal mask
            #pragma unroll
            for (int r = 0; r < 16; ++r) {
                const int kvr = (r & 3) + 8 * (r >> 2) + 4 * hi;
                if (kb + kvr > qpos) s[r] = -1e38f;
            }
        }

        // row(=q) max: 15 in-register fmax + one cross-half shuffle
        float b0 = fmaxf(fmaxf(s[0], s[1]), fmaxf(s[2], s[3]));
        float b1 = fmaxf(fmaxf(s[4], s[5]), fmaxf(s[6], s[7]));
        float b2 = fmaxf(fmaxf(s[8], s[9]), fmaxf(s[10], s[11]));
        float b3 = fmaxf(fmaxf(s[12], s[13]), fmaxf(s[14], s[15]));
        float bm = fmaxf(fmaxf(b0, b1), fmaxf(b2, b3));
        bm = fmaxf(bm, __shfl_xor(bm, 32));
        const float bmS = bm * SCALE;

        if (__any(bmS > m)) {          // rescale only when a max grew (exact)
            const float mn = fmaxf(m, bmS);
            const float al = __expf(m - mn);
            m = mn;
            l *= al;
            #pragma unroll
            for (int n = 0; n < 4; ++n)
                #pragma unroll
                for (int r = 0; r < 16; ++r) o[n][r] *= al;
        }

        float p[16];
        float rs = 0.f;
        #pragma unroll
        for (int r = 0; r < 16; ++r) {
            p[r] = __expf(fmaf(s[r], SCALE, -m));
            rs += p[r];
        }
        rs += __shfl_xor(rs, 32);
        l += rs;

        // P^T B-fragment assembly, fully in-register.
        // lane holds P[kv = (r&3)+8*(r>>2)+4*hi][q=l31]; fragment needs
        // P[kv = ks*16 + hi*8 + j].  8 packs + 4 xor-32 shuffles + selects.
        u32 P01 = (u32)f2bf(p[0])  | ((u32)f2bf(p[1])  << 16);
        u32 P23 = (u32)f2bf(p[2])  | ((u32)f2bf(p[3])  << 16);
        u32 P45 = (u32)f2bf(p[4])  | ((u32)f2bf(p[5])  << 16);
        u32 P67 = (u32)f2bf(p[6])  | ((u32)f2bf(p[7])  << 16);
        u32 P89 = (u32)f2bf(p[8])  | ((u32)f2bf(p[9])  << 16);
        u32 Pab = (u32)f2bf(p[10]) | ((u32)f2bf(p[11]) << 16);
        u32 Pcd = (u32)f2bf(p[12]) | ((u32)f2bf(p[13]) << 16);
        u32 Pef = (u32)f2bf(p[14]) | ((u32)f2bf(p[15]) << 16);
        u32 x1 = __shfl_xor(hi ? P01 : P45, 32);
        u32 x2 = __shfl_xor(hi ? P23 : P67, 32);
        u32 x3 = __shfl_xor(hi ? P89 : Pcd, 32);
        u32 x4 = __shfl_xor(hi ? Pab : Pef, 32);

        union { short8 v; u32 w[4]; } f0, f1;
        f0.w[0] = hi ? x1 : P01;  f0.w[1] = hi ? x2 : P23;
        f0.w[2] = hi ? P45 : x1;  f0.w[3] = hi ? P67 : x2;
        f1.w[0] = hi ? x3 : P89;  f1.w[1] = hi ? x4 : Pab;
        f1.w[2] = hi ? Pcd : x3;  f1.w[3] = hi ? Pef : x4;

        // O^T[d][q] += V^T[d][kv] * P^T[kv][q]
        const u16* Vtp = Vp + kb;
        __builtin_amdgcn_s_setprio(1);
        #pragma unroll
        for (int n = 0; n < 4; ++n) {
            o[n] = __builtin_amdgcn_mfma_f32_32x32x16_bf16(
                *(const short8*)(Vtp + (size_t)(n * 32) * S_), f0.v, o[n], 0, 0, 0);
            o[n] = __builtin_amdgcn_mfma_f32_32x32x16_bf16(
                *(const short8*)(Vtp + (size_t)(n * 32) * S_ + 16), f1.v, o[n], 0, 0, 0);
        }
        __builtin_amdgcn_s_setprio(0);
    }

    // epilogue: lane holds O^T[d = n*32 + (r&3)+8*(r>>2)+4*hi][q = l31]
    const float inv = 1.0f / l;
    u16* dst = AO + ((size_t)(b * S_) + q0 + l31) * (NH_ * HD_) + h * HD_ + hi * 4;
    #pragma unroll
    for (int n = 0; n < 4; ++n)
        #pragma unroll
        for (int rg = 0; rg < 4; ++rg) {
            u32 lo  = (u32)f2bf(o[n][rg * 4 + 0] * inv) |
                      ((u32)f2bf(o[n][rg * 4 + 1] * inv) << 16);
            u32 hi2 = (u32)f2bf(o[n][rg * 4 + 2] * inv) |
                      ((u32)f2bf(o[n][rg * 4 + 3] * inv) << 16);
            *(uint2*)(dst + n * 32 + rg * 8) = make_uint2(lo, hi2);
        }
}

// ---------------------------------------------------------------------------
extern "C" void kernel_launch(void* const* d_in, const int* in_sizes, int n_in,
                              void* d_out, int out_size, void* d_ws, size_t ws_size,
                              hipStream_t stream)
{
    const float* hs   = (const float*)d_in[0];
    const float* cosp = (const float*)d_in[1];
    const float* sinp = (const float*)d_in[2];
    const float* wq   = (const float*)d_in[3];
    const float* wk   = (const float*)d_in[4];
    const float* wv   = (const float*)d_in[5];
    const float* wo   = (const float*)d_in[6];
    float* out = (float*)d_out;
    char* ws = (char*)d_ws;

    u16* qkv_raw = (u16*)ws;                                  // 48 MB
    u16* AO      = (u16*)ws;                                  // 32 MB (reuse)
    u16* Qb = (u16*)(ws + (size_t)48 * 1024 * 1024);          // 32 MB
    u16* Kb = (u16*)(ws + (size_t)80 * 1024 * 1024);          //  8 MB
    u16* Vt = (u16*)(ws + (size_t)88 * 1024 * 1024);          //  8 MB

    gemm_bt<false, false><<<dim3(NQKV / 128, M_TOK / 128), 256, 0, stream>>>(
        hs, wq, wk, wv, NH_ * HD_, NH_ * HD_ + NKV_ * HD_,
        qkv_raw, M_TOK, NQKV, D_);

    rope_reshape<<<40960, 256, 0, stream>>>(qkv_raw, cosp, sinp, Qb, Kb);

    v_transpose<<<256, 256, 0, stream>>>(qkv_raw, Vt);

    flash_attn<<<1024, 256, 0, stream>>>(Qb, Kb, Vt, AO);

    gemm_bt<true, true><<<dim3(D_ / 128, M_TOK / 128), 256, 0, stream>>>(
        AO, wo, wo, wo, D_, 2 * D_, out, M_TOK, D_, NH_ * HD_);
}

// Round 2
// 970.199 us; speedup vs baseline: 1.4759x; 1.1381x over previous
//
#include <hip/hip_runtime.h>

#define B_    2
#define S_    2048
#define D_    4096
#define NH_   32
#define NKV_  8
#define HD_   128
#define M_TOK 4096           // B_*S_
#define NQKV  6144           // (NH_+2*NKV_)*HD_
#define SCALE 0.08838834764831845f

typedef unsigned short u16;
typedef unsigned int   u32;
typedef __attribute__((ext_vector_type(8))) short short8;
typedef __attribute__((ext_vector_type(4))) float floatx4;
typedef __attribute__((ext_vector_type(16))) float floatx16;

typedef const __attribute__((address_space(1))) void cg_void;
typedef __attribute__((address_space(3))) void lds_void;
#define GP(x) ((cg_void*)(x))
#define LP(x) ((lds_void*)(x))

__device__ inline u16 f2bf(float f) {
    u32 u = __float_as_uint(f);
    u = (u + 0x7FFFu + ((u >> 16) & 1u)) >> 16;
    return (u16)u;
}
__device__ inline float bf2f(u16 u) {
    return __uint_as_float(((u32)u) << 16);
}

// ---------------------------------------------------------------------------
// f32 -> bf16 streaming converter (one-time; hoists conversion out of GEMM).
// n8 = n/8; all sizes here are multiples of 2048*8.
// ---------------------------------------------------------------------------
__global__ __launch_bounds__(256) void cvt_bf16(
    const float* __restrict__ src, u16* __restrict__ dst, int n8)
{
    int id = blockIdx.x * 256 + threadIdx.x;
    if (id >= n8) return;
    size_t i = (size_t)id * 8;
    float4 a = *(const float4*)(src + i);
    float4 b = *(const float4*)(src + i + 4);
    __align__(16) u16 t[8];
    t[0] = f2bf(a.x); t[1] = f2bf(a.y); t[2] = f2bf(a.z); t[3] = f2bf(a.w);
    t[4] = f2bf(b.x); t[5] = f2bf(b.y); t[6] = f2bf(b.z); t[7] = f2bf(b.w);
    *(short8*)(dst + i) = *(short8*)t;
}

// ---------------------------------------------------------------------------
// bf16 B^T GEMM, m97 structure: C[m,n] = sum_k A[m,k] * B[n,k].
// Linear [128][32] LDS tiles staged via global_load_lds width=16
// (zero staging VALU, no register round-trip), 2-barrier K-loop,
// 16x16x32 MFMA, 4x4 acc per wave.
// ---------------------------------------------------------------------------
template<bool OUT_F32>
__global__ __launch_bounds__(256) void gemm_bf16(
    const u16* __restrict__ A, const u16* __restrict__ Bw,
    void* __restrict__ Cp, int M, int N, int K)
{
    __shared__ __align__(16) u16 As[128][32];
    __shared__ __align__(16) u16 Bs[128][32];

    const int tid  = threadIdx.x;
    const int lane = tid & 63, wave = tid >> 6;
    const int quad = lane >> 4, l16 = lane & 15;
    const int m0 = blockIdx.y * 128, n0 = blockIdx.x * 128;
    const int wm = (wave >> 1) * 64, wn = (wave & 1) * 64;

    // staging: thread handles 16B at (row = tid>>2, col = (tid&3)*8);
    // per-wave LDS dest is linear in tid (wave-uniform base + lane*16).
    const int srow = tid >> 2, scol = (tid & 3) * 8;
    const u16* Ap0 = A  + (size_t)(m0 + srow) * K + scol;
    const u16* Bp0 = Bw + (size_t)(n0 + srow) * K + scol;
    u16* Asd = &As[srow][scol];
    u16* Bsd = &Bs[srow][scol];

    floatx4 acc[4][4];
    #pragma unroll
    for (int i = 0; i < 4; ++i)
        #pragma unroll
        for (int j = 0; j < 4; ++j) acc[i][j] = (floatx4){0.f, 0.f, 0.f, 0.f};

    for (int k0 = 0; k0 < K; k0 += 32) {
        __builtin_amdgcn_global_load_lds(GP(Ap0 + k0),                    LP(Asd),            16, 0, 0);
        __builtin_amdgcn_global_load_lds(GP(Ap0 + (size_t)64 * K + k0),   LP(Asd + 64 * 32),  16, 0, 0);
        __builtin_amdgcn_global_load_lds(GP(Bp0 + k0),                    LP(Bsd),            16, 0, 0);
        __builtin_amdgcn_global_load_lds(GP(Bp0 + (size_t)64 * K + k0),   LP(Bsd + 64 * 32),  16, 0, 0);
        __syncthreads();

        short8 af[4], bfv[4];
        #pragma unroll
        for (int i = 0; i < 4; ++i)
            af[i] = *(const short8*)&As[wm + i * 16 + l16][quad * 8];
        #pragma unroll
        for (int j = 0; j < 4; ++j)
            bfv[j] = *(const short8*)&Bs[wn + j * 16 + l16][quad * 8];
        #pragma unroll
        for (int i = 0; i < 4; ++i)
            #pragma unroll
            for (int j = 0; j < 4; ++j)
                acc[i][j] = __builtin_amdgcn_mfma_f32_16x16x32_bf16(
                    af[i], bfv[j], acc[i][j], 0, 0, 0);
        __syncthreads();
    }

    #pragma unroll
    for (int i = 0; i < 4; ++i)
        #pragma unroll
        for (int j = 0; j < 4; ++j)
            #pragma unroll
            for (int r = 0; r < 4; ++r) {
                int row = m0 + wm + i * 16 + quad * 4 + r;
                int col = n0 + wn + j * 16 + l16;
                float v = acc[i][j][r];
                if constexpr (OUT_F32)
                    ((float*)Cp)[(size_t)row * N + col] = v;
                else
                    ((u16*)Cp)[(size_t)row * N + col] = f2bf(v);
            }
}

// ---------------------------------------------------------------------------
// RoPE + head-major reshape for Q and K (unchanged).
// ---------------------------------------------------------------------------
__global__ __launch_bounds__(256) void rope_reshape(
    const u16* __restrict__ qkv, const float* __restrict__ cosp,
    const float* __restrict__ sinp, u16* __restrict__ Q, u16* __restrict__ Kb)
{
    const size_t QN = (size_t)M_TOK * NH_ * 64;
    size_t id = (size_t)blockIdx.x * 256 + threadIdx.x;
    if (id < QN) {
        int j = id & 63; int h = (id >> 6) & (NH_ - 1); int tok = (int)(id >> 11);
        int b = tok >> 11, s = tok & (S_ - 1);
        float c  = cosp[(size_t)tok * HD_ + j];
        float sn = sinp[(size_t)tok * HD_ + j];
        float x1 = bf2f(qkv[(size_t)tok * NQKV + h * HD_ + j]);
        float x2 = bf2f(qkv[(size_t)tok * NQKV + h * HD_ + 64 + j]);
        size_t o = ((size_t)(b * NH_ + h) * S_ + s) * HD_ + j;
        Q[o]      = f2bf(x1 * c - x2 * sn);
        Q[o + 64] = f2bf(x2 * c + x1 * sn);
    } else {
        size_t kid = id - QN;
        int j = kid & 63; int h = (kid >> 6) & (NKV_ - 1); int tok = (int)(kid >> 9);
        int b = tok >> 11, s = tok & (S_ - 1);
        float c  = cosp[(size_t)tok * HD_ + j];
        float sn = sinp[(size_t)tok * HD_ + j];
        float x1 = bf2f(qkv[(size_t)tok * NQKV + 4096 + h * HD_ + j]);
        float x2 = bf2f(qkv[(size_t)tok * NQKV + 4096 + h * HD_ + 64 + j]);
        size_t o = ((size_t)(b * NKV_ + h) * S_ + s) * HD_ + j;
        Kb[o]      = f2bf(x1 * c - x2 * sn);
        Kb[o + 64] = f2bf(x2 * c + x1 * sn);
    }
}

// ---------------------------------------------------------------------------
// V transpose (unchanged): qkv V part -> Vt[b,hk,d,s]
// ---------------------------------------------------------------------------
__global__ __launch_bounds__(256) void v_transpose(
    const u16* __restrict__ qkv, u16* __restrict__ Vt)
{
    __shared__ __align__(16) u16 T[128][136];
    int bidx = blockIdx.x;
    int st = bidx & 15; int h = (bidx >> 4) & 7; int b = bidx >> 7;
    int s0 = st * 128;
    int tid = threadIdx.x;
    #pragma unroll
    for (int i = 0; i < 8; ++i) {
        int row = i * 16 + (tid >> 4); int cg = tid & 15;
        const u16* src = qkv + (size_t)(b * S_ + s0 + row) * NQKV + 5120 + h * HD_ + cg * 8;
        *(short8*)&T[row][cg * 8] = *(const short8*)src;
    }
    __syncthreads();
    #pragma unroll
    for (int i = 0; i < 8; ++i) {
        int d = i * 16 + (tid >> 4); int cg = tid & 15;
        __align__(16) u16 tmp[8];
        #pragma unroll
        for (int j = 0; j < 8; ++j) tmp[j] = T[cg * 8 + j][d];
        *(short8*)(Vt + ((size_t)(b * NKV_ + h) * HD_ + d) * S_ + s0 + cg * 8) =
            *(short8*)tmp;
    }
}

// ---------------------------------------------------------------------------
// Flash attention v3 (unchanged from round 1; verified).
// ---------------------------------------------------------------------------
__global__ __launch_bounds__(256) void flash_attn(
    const u16* __restrict__ Q, const u16* __restrict__ Kb,
    const u16* __restrict__ Vt, u16* __restrict__ AO)
{
    const int tid  = threadIdx.x;
    const int wave = tid >> 6, lane = tid & 63;
    const int l31 = lane & 31, hi = lane >> 5;

    const int i    = blockIdx.x;
    const int xcd  = i & 7;           // blockIdx round-robins XCDs
    const int slot = i >> 3;
    const int g    = slot & 3;        // q-head within kv group
    const int qb   = 15 - ((slot >> 2) & 15);   // longest blocks first
    const int b    = slot >> 6;
    const int hk   = xcd;             // one kv head per XCD -> L2-resident
    const int h    = hk * 4 + g;
    const int qt   = qb * 4 + wave;   // 32-row q-tile index [0,64)
    const int q0   = qt * 32;
    const int qpos = q0 + l31;

    const u16* Kbase = Kb + (size_t)(b * NKV_ + hk) * S_ * HD_;
    const u16* Vbase = Vt + (size_t)(b * NKV_ + hk) * HD_ * S_;

    // Q fragments: B-operand, col=l31 (q row), k = c*16 + hi*8 + j
    const u16* Qp = Q + ((size_t)(b * NH_ + h) * S_ + q0 + l31) * HD_ + hi * 8;
    short8 qf[8];
    #pragma unroll
    for (int c = 0; c < 8; ++c) qf[c] = *(const short8*)(Qp + c * 16);

    float m = -1e30f, l = 0.f;
    floatx16 o[4];
    #pragma unroll
    for (int n = 0; n < 4; ++n)
        #pragma unroll
        for (int r = 0; r < 16; ++r) o[n][r] = 0.f;

    const u16* Kp = Kbase + (size_t)l31 * HD_ + hi * 8;   // A-op: row=l31(kv)
    const u16* Vp = Vbase + (size_t)l31 * S_ + hi * 8;    // A-op: row=l31(d)

    for (int t = 0; t <= qt; ++t) {
        const int kb = t * 32;
        const u16* Kt = Kp + (size_t)kb * HD_;

        // S^T[kv][q] via two independent accumulator chains
        floatx16 ca, cb;
        #pragma unroll
        for (int r = 0; r < 16; ++r) { ca[r] = 0.f; cb[r] = 0.f; }
        __builtin_amdgcn_s_setprio(1);
        #pragma unroll
        for (int c = 0; c < 8; c += 2) {
            ca = __builtin_amdgcn_mfma_f32_32x32x16_bf16(
                *(const short8*)(Kt + c * 16), qf[c], ca, 0, 0, 0);
            cb = __builtin_amdgcn_mfma_f32_32x32x16_bf16(
                *(const short8*)(Kt + (c + 1) * 16), qf[c + 1], cb, 0, 0, 0);
        }
        __builtin_amdgcn_s_setprio(0);

        float s[16];
        #pragma unroll
        for (int r = 0; r < 16; ++r) s[r] = ca[r] + cb[r];

        if (t == qt) {                 // diagonal tile: causal mask
            #pragma unroll
            for (int r = 0; r < 16; ++r) {
                const int kvr = (r & 3) + 8 * (r >> 2) + 4 * hi;
                if (kb + kvr > qpos) s[r] = -1e38f;
            }
        }

        // row(=q) max: 15 in-register fmax + one cross-half shuffle
        float b0 = fmaxf(fmaxf(s[0], s[1]), fmaxf(s[2], s[3]));
        float b1 = fmaxf(fmaxf(s[4], s[5]), fmaxf(s[6], s[7]));
        float b2 = fmaxf(fmaxf(s[8], s[9]), fmaxf(s[10], s[11]));
        float b3 = fmaxf(fmaxf(s[12], s[13]), fmaxf(s[14], s[15]));
        float bm = fmaxf(fmaxf(b0, b1), fmaxf(b2, b3));
        bm = fmaxf(bm, __shfl_xor(bm, 32));
        const float bmS = bm * SCALE;

        if (__any(bmS > m)) {          // rescale only when a max grew (exact)
            const float mn = fmaxf(m, bmS);
            const float al = __expf(m - mn);
            m = mn;
            l *= al;
            #pragma unroll
            for (int n = 0; n < 4; ++n)
                #pragma unroll
                for (int r = 0; r < 16; ++r) o[n][r] *= al;
        }

        float p[16];
        float rs = 0.f;
        #pragma unroll
        for (int r = 0; r < 16; ++r) {
            p[r] = __expf(fmaf(s[r], SCALE, -m));
            rs += p[r];
        }
        rs += __shfl_xor(rs, 32);
        l += rs;

        // P^T B-fragment assembly, fully in-register.
        u32 P01 = (u32)f2bf(p[0])  | ((u32)f2bf(p[1])  << 16);
        u32 P23 = (u32)f2bf(p[2])  | ((u32)f2bf(p[3])  << 16);
        u32 P45 = (u32)f2bf(p[4])  | ((u32)f2bf(p[5])  << 16);
        u32 P67 = (u32)f2bf(p[6])  | ((u32)f2bf(p[7])  << 16);
        u32 P89 = (u32)f2bf(p[8])  | ((u32)f2bf(p[9])  << 16);
        u32 Pab = (u32)f2bf(p[10]) | ((u32)f2bf(p[11]) << 16);
        u32 Pcd = (u32)f2bf(p[12]) | ((u32)f2bf(p[13]) << 16);
        u32 Pef = (u32)f2bf(p[14]) | ((u32)f2bf(p[15]) << 16);
        u32 x1 = __shfl_xor(hi ? P01 : P45, 32);
        u32 x2 = __shfl_xor(hi ? P23 : P67, 32);
        u32 x3 = __shfl_xor(hi ? P89 : Pcd, 32);
        u32 x4 = __shfl_xor(hi ? Pab : Pef, 32);

        union { short8 v; u32 w[4]; } f0, f1;
        f0.w[0] = hi ? x1 : P01;  f0.w[1] = hi ? x2 : P23;
        f0.w[2] = hi ? P45 : x1;  f0.w[3] = hi ? P67 : x2;
        f1.w[0] = hi ? x3 : P89;  f1.w[1] = hi ? x4 : Pab;
        f1.w[2] = hi ? Pcd : x3;  f1.w[3] = hi ? Pef : x4;

        // O^T[d][q] += V^T[d][kv] * P^T[kv][q]
        const u16* Vtp = Vp + kb;
        __builtin_amdgcn_s_setprio(1);
        #pragma unroll
        for (int n = 0; n < 4; ++n) {
            o[n] = __builtin_amdgcn_mfma_f32_32x32x16_bf16(
                *(const short8*)(Vtp + (size_t)(n * 32) * S_), f0.v, o[n], 0, 0, 0);
            o[n] = __builtin_amdgcn_mfma_f32_32x32x16_bf16(
                *(const short8*)(Vtp + (size_t)(n * 32) * S_ + 16), f1.v, o[n], 0, 0, 0);
        }
        __builtin_amdgcn_s_setprio(0);
    }

    // epilogue: lane holds O^T[d = n*32 + (r&3)+8*(r>>2)+4*hi][q = l31]
    const float inv = 1.0f / l;
    u16* dst = AO + ((size_t)(b * S_) + q0 + l31) * (NH_ * HD_) + h * HD_ + hi * 4;
    #pragma unroll
    for (int n = 0; n < 4; ++n)
        #pragma unroll
        for (int rg = 0; rg < 4; ++rg) {
            u32 lo  = (u32)f2bf(o[n][rg * 4 + 0] * inv) |
                      ((u32)f2bf(o[n][rg * 4 + 1] * inv) << 16);
            u32 hi2 = (u32)f2bf(o[n][rg * 4 + 2] * inv) |
                      ((u32)f2bf(o[n][rg * 4 + 3] * inv) << 16);
            *(uint2*)(dst + n * 32 + rg * 8) = make_uint2(lo, hi2);
        }
}

// ---------------------------------------------------------------------------
// Workspace layout (128 MiB total, stream-ordered reuse):
//   [0,48)    qkv_raw  -> AO (reuse [0,32)) after v_transpose
//   [48,96)   Wqkv bf16 (live only through QKV GEMM)
//             -> Qb [48,80), Kb [80,88), Vt [88,96) written by rope/v_t
//   [96,128)  hs bf16 (live through QKV GEMM) -> Wo bf16 (after flash)
// ---------------------------------------------------------------------------
extern "C" void kernel_launch(void* const* d_in, const int* in_sizes, int n_in,
                              void* d_out, int out_size, void* d_ws, size_t ws_size,
                              hipStream_t stream)
{
    const float* hs   = (const float*)d_in[0];
    const float* cosp = (const float*)d_in[1];
    const float* sinp = (const float*)d_in[2];
    const float* wq   = (const float*)d_in[3];
    const float* wk   = (const float*)d_in[4];
    const float* wv   = (const float*)d_in[5];
    const float* wo   = (const float*)d_in[6];
    float* out = (float*)d_out;
    char* ws = (char*)d_ws;

    const size_t MB = 1024 * 1024;
    u16* qkv_raw = (u16*)ws;                      // 48 MiB
    u16* AO      = (u16*)ws;                      // 32 MiB (reuse)
    u16* Wqkv    = (u16*)(ws + 48 * MB);          // 48 MiB (transient)
    u16* Qb      = (u16*)(ws + 48 * MB);          // 32 MiB (after QKV GEMM)
    u16* Kb      = (u16*)(ws + 80 * MB);          //  8 MiB
    u16* Vt      = (u16*)(ws + 88 * MB);          //  8 MiB
    u16* hs_bf   = (u16*)(ws + 96 * MB);          // 32 MiB
    u16* Wo_bf   = (u16*)(ws + 96 * MB);          // 32 MiB (after flash)

    // one-time f32 -> bf16 conversions
    cvt_bf16<<<8192, 256, 0, stream>>>(hs, hs_bf, (M_TOK * D_) / 8);
    cvt_bf16<<<8192, 256, 0, stream>>>(wq, Wqkv, (NH_ * HD_ * D_) / 8);
    cvt_bf16<<<2048, 256, 0, stream>>>(wk, Wqkv + (size_t)NH_ * HD_ * D_, (NKV_ * HD_ * D_) / 8);
    cvt_bf16<<<2048, 256, 0, stream>>>(wv, Wqkv + (size_t)(NH_ + NKV_) * HD_ * D_, (NKV_ * HD_ * D_) / 8);

    gemm_bf16<false><<<dim3(NQKV / 128, M_TOK / 128), 256, 0, stream>>>(
        hs_bf, Wqkv, qkv_raw, M_TOK, NQKV, D_);

    rope_reshape<<<40960, 256, 0, stream>>>(qkv_raw, cosp, sinp, Qb, Kb);

    v_transpose<<<256, 256, 0, stream>>>(qkv_raw, Vt);

    flash_attn<<<1024, 256, 0, stream>>>(Qb, Kb, Vt, AO);

    cvt_bf16<<<8192, 256, 0, stream>>>(wo, Wo_bf, (D_ * NH_ * HD_) / 8);

    gemm_bf16<true><<<dim3(D_ / 128, M_TOK / 128), 256, 0, stream>>>(
        AO, Wo_bf, out, M_TOK, D_, NH_ * HD_);
}

// Round 4
// 882.132 us; speedup vs baseline: 1.6232x; 1.0998x over previous
//
#include <hip/hip_runtime.h>

#define B_    2
#define S_    2048
#define D_    4096
#define NH_   32
#define NKV_  8
#define HD_   128
#define M_TOK 4096           // B_*S_
#define NQKV  6144           // (NH_+2*NKV_)*HD_
#define SCALE 0.08838834764831845f

typedef unsigned short u16;
typedef unsigned int   u32;
typedef __attribute__((ext_vector_type(8))) short short8;
typedef __attribute__((ext_vector_type(4))) float floatx4;
typedef __attribute__((ext_vector_type(16))) float floatx16;

typedef const __attribute__((address_space(1))) void cg_void;
typedef __attribute__((address_space(3))) void lds_void;
#define GP(x) ((cg_void*)(x))
#define LP(x) ((lds_void*)(x))

__device__ inline u16 f2bf(float f) {
    u32 u = __float_as_uint(f);
    u = (u + 0x7FFFu + ((u >> 16) & 1u)) >> 16;
    return (u16)u;
}
__device__ inline float bf2f(u16 u) {
    return __uint_as_float(((u32)u) << 16);
}

// ---------------------------------------------------------------------------
// f32 -> bf16 streaming converter (unchanged).
// ---------------------------------------------------------------------------
__global__ __launch_bounds__(256) void cvt_bf16(
    const float* __restrict__ src, u16* __restrict__ dst, int n8)
{
    int id = blockIdx.x * 256 + threadIdx.x;
    if (id >= n8) return;
    size_t i = (size_t)id * 8;
    float4 a = *(const float4*)(src + i);
    float4 b = *(const float4*)(src + i + 4);
    __align__(16) u16 t[8];
    t[0] = f2bf(a.x); t[1] = f2bf(a.y); t[2] = f2bf(a.z); t[3] = f2bf(a.w);
    t[4] = f2bf(b.x); t[5] = f2bf(b.y); t[6] = f2bf(b.z); t[7] = f2bf(b.w);
    *(short8*)(dst + i) = *(short8*)t;
}

// ---------------------------------------------------------------------------
// Deep-pipelined bf16 B^T GEMM:  C[m,n] = sum_k A[m,k] * B[n,k].
// BM=256 BN=128 BK=64, 512 threads = 8 waves (4M x 2N), 64x64 per wave.
// - double-buffered 96 KiB LDS; stage tile t+2 at boundary of tile t;
//   per-wave s_waitcnt vmcnt(6): tile t+1's 6 loads stay in flight across
//   the whole compute of tile t (counted, never drained in main loop).
// - LDS XOR swizzle (slot ^= row&7) applied to global SOURCE address and
//   ds_read address (linear global_load_lds dest) -> conflict-free b128.
// - per-phase barriers + setprio around 16-MFMA clusters (2 phases/tile).
// - sched_barrier(0) pins staging/waitcnt ordering (raw s_barrier is not a
//   compiler memory fence).
// - bijective XCD-chunked block swizzle (grids are multiples of 8).
// Race-freedom: writes to buf[t&1] issue only after the post-MFMA barrier
// where all waves finished reading it; vmcnt(6)+barrier at each boundary
// guarantees tile t+1 resident before any wave reads it.
// ---------------------------------------------------------------------------
#define GBK 64
#define A_U16 (256 * GBK)      // 16384 u16 = 32 KiB
#define B_U16 (128 * GBK)      //  8192 u16 = 16 KiB
#define BUF_U16 (A_U16 + B_U16)

template<bool OUT_F32>
__global__ __launch_bounds__(512) void gemm_pipe(
    const u16* __restrict__ A, const u16* __restrict__ Bw,
    void* __restrict__ Cp, int M, int N, int K)
{
    __shared__ __align__(16) u16 smem[2][BUF_U16];   // 96 KiB

    const int tid  = threadIdx.x;
    const int lane = tid & 63, wave = tid >> 6;
    const int quad = lane >> 4, l16 = lane & 15;

    // bijective XCD-chunked swizzle (nwg % 8 == 0 for both call sites)
    const int gx  = gridDim.x;
    const int lin = blockIdx.y * gx + blockIdx.x;
    const int nwg = gx * gridDim.y;
    const int wg  = (lin & 7) * (nwg >> 3) + (lin >> 3);
    const int by  = wg / gx, bx = wg - by * gx;
    const int m0 = by * 256, n0 = bx * 128;

    const int wm = (wave >> 1) * 64;   // 4 M-waves
    const int wn = (wave & 1) * 64;    // 2 N-waves

    // staging geometry: thread -> (row = q*64 + tid>>3, slot = tid&7);
    // LDS dest linear in tid (wave-uniform base + lane*16); swizzle lives
    // in the global source column slot: src_slot = slot ^ (row & 7).
    const int srow  = tid >> 3;
    const int sslot = tid & 7;
    const u16* Asrc = A  + (size_t)(m0 + srow) * K + (size_t)((sslot ^ (srow & 7)) * 8);
    const u16* Bsrc = Bw + (size_t)(n0 + srow) * K + (size_t)((sslot ^ (srow & 7)) * 8);

    const int NT = K / GBK;
    const int sw = l16 & 7;            // fragment read swizzle

    floatx4 acc[4][4];
    #pragma unroll
    for (int i = 0; i < 4; ++i)
        #pragma unroll
        for (int j = 0; j < 4; ++j) acc[i][j] = (floatx4){0.f, 0.f, 0.f, 0.f};

    // prologue: stage tiles 0 and 1; wait for tile 0 (leave 6 in flight)
    #pragma unroll
    for (int tb = 0; tb < 2; ++tb) {
        u16* Ad = &smem[tb][0]     + tid * 8;
        u16* Bd = &smem[tb][A_U16] + tid * 8;
        const size_t k0 = (size_t)tb * GBK;
        #pragma unroll
        for (int q = 0; q < 4; ++q)
            __builtin_amdgcn_global_load_lds(GP(Asrc + (size_t)q * 64 * K + k0),
                                             LP(Ad + q * 4096), 16, 0, 0);
        #pragma unroll
        for (int q = 0; q < 2; ++q)
            __builtin_amdgcn_global_load_lds(GP(Bsrc + (size_t)q * 64 * K + k0),
                                             LP(Bd + q * 4096), 16, 0, 0);
    }
    __builtin_amdgcn_sched_barrier(0);
    asm volatile("s_waitcnt vmcnt(6)" ::: "memory");
    __builtin_amdgcn_sched_barrier(0);
    __builtin_amdgcn_s_barrier();

    #pragma unroll 1
    for (int t = 0; t < NT; ++t) {
        const u16* Ab = &smem[t & 1][0]     + (size_t)(wm + l16) * GBK;
        const u16* Bb = &smem[t & 1][A_U16] + (size_t)(wn + l16) * GBK;

        #pragma unroll
        for (int kh = 0; kh < 2; ++kh) {
            const int sl = ((kh * 4 + quad) ^ sw) * 8;
            short8 af[4], bfv[4];
            #pragma unroll
            for (int i = 0; i < 4; ++i)
                af[i] = *(const short8*)(Ab + i * 16 * GBK + sl);
            #pragma unroll
            for (int j = 0; j < 4; ++j)
                bfv[j] = *(const short8*)(Bb + j * 16 * GBK + sl);

            __builtin_amdgcn_s_barrier();
            __builtin_amdgcn_s_setprio(1);
            #pragma unroll
            for (int i = 0; i < 4; ++i)
                #pragma unroll
                for (int j = 0; j < 4; ++j)
                    acc[i][j] = __builtin_amdgcn_mfma_f32_16x16x32_bf16(
                        af[i], bfv[j], acc[i][j], 0, 0, 0);
            __builtin_amdgcn_s_setprio(0);
            __builtin_amdgcn_s_barrier();
        }

        if (t + 1 == NT) break;

        __builtin_amdgcn_sched_barrier(0);
        if (t + 2 < NT) {
            // stage tile t+2 into the buffer just consumed (all waves have
            // passed the post-MFMA barrier -> no reader left)
            u16* Ad = &smem[t & 1][0]     + tid * 8;
            u16* Bd = &smem[t & 1][A_U16] + tid * 8;
            const size_t k0 = (size_t)(t + 2) * GBK;
            #pragma unroll
            for (int q = 0; q < 4; ++q)
                __builtin_amdgcn_global_load_lds(GP(Asrc + (size_t)q * 64 * K + k0),
                                                 LP(Ad + q * 4096), 16, 0, 0);
            #pragma unroll
            for (int q = 0; q < 2; ++q)
                __builtin_amdgcn_global_load_lds(GP(Bsrc + (size_t)q * 64 * K + k0),
                                                 LP(Bd + q * 4096), 16, 0, 0);
            __builtin_amdgcn_sched_barrier(0);
            asm volatile("s_waitcnt vmcnt(6)" ::: "memory");   // tile t+1 ready
        } else {
            asm volatile("s_waitcnt vmcnt(0)" ::: "memory");   // tail drain
        }
        __builtin_amdgcn_sched_barrier(0);
        __builtin_amdgcn_s_barrier();
    }

    #pragma unroll
    for (int i = 0; i < 4; ++i)
        #pragma unroll
        for (int j = 0; j < 4; ++j)
            #pragma unroll
            for (int r = 0; r < 4; ++r) {
                int row = m0 + wm + i * 16 + quad * 4 + r;
                int col = n0 + wn + j * 16 + l16;
                float v = acc[i][j][r];
                if constexpr (OUT_F32)
                    ((float*)Cp)[(size_t)row * N + col] = v;
                else
                    ((u16*)Cp)[(size_t)row * N + col] = f2bf(v);
            }
}

// ---------------------------------------------------------------------------
// RoPE + head-major reshape for Q and K (unchanged).
// ---------------------------------------------------------------------------
__global__ __launch_bounds__(256) void rope_reshape(
    const u16* __restrict__ qkv, const float* __restrict__ cosp,
    const float* __restrict__ sinp, u16* __restrict__ Q, u16* __restrict__ Kb)
{
    const size_t QN = (size_t)M_TOK * NH_ * 64;
    size_t id = (size_t)blockIdx.x * 256 + threadIdx.x;
    if (id < QN) {
        int j = id & 63; int h = (id >> 6) & (NH_ - 1); int tok = (int)(id >> 11);
        int b = tok >> 11, s = tok & (S_ - 1);
        float c  = cosp[(size_t)tok * HD_ + j];
        float sn = sinp[(size_t)tok * HD_ + j];
        float x1 = bf2f(qkv[(size_t)tok * NQKV + h * HD_ + j]);
        float x2 = bf2f(qkv[(size_t)tok * NQKV + h * HD_ + 64 + j]);
        size_t o = ((size_t)(b * NH_ + h) * S_ + s) * HD_ + j;
        Q[o]      = f2bf(x1 * c - x2 * sn);
        Q[o + 64] = f2bf(x2 * c + x1 * sn);
    } else {
        size_t kid = id - QN;
        int j = kid & 63; int h = (kid >> 6) & (NKV_ - 1); int tok = (int)(kid >> 9);
        int b = tok >> 11, s = tok & (S_ - 1);
        float c  = cosp[(size_t)tok * HD_ + j];
        float sn = sinp[(size_t)tok * HD_ + j];
        float x1 = bf2f(qkv[(size_t)tok * NQKV + 4096 + h * HD_ + j]);
        float x2 = bf2f(qkv[(size_t)tok * NQKV + 4096 + h * HD_ + 64 + j]);
        size_t o = ((size_t)(b * NKV_ + h) * S_ + s) * HD_ + j;
        Kb[o]      = f2bf(x1 * c - x2 * sn);
        Kb[o + 64] = f2bf(x2 * c + x1 * sn);
    }
}

// ---------------------------------------------------------------------------
// V transpose (unchanged): qkv V part -> Vt[b,hk,d,s]
// ---------------------------------------------------------------------------
__global__ __launch_bounds__(256) void v_transpose(
    const u16* __restrict__ qkv, u16* __restrict__ Vt)
{
    __shared__ __align__(16) u16 T[128][136];
    int bidx = blockIdx.x;
    int st = bidx & 15; int h = (bidx >> 4) & 7; int b = bidx >> 7;
    int s0 = st * 128;
    int tid = threadIdx.x;
    #pragma unroll
    for (int i = 0; i < 8; ++i) {
        int row = i * 16 + (tid >> 4); int cg = tid & 15;
        const u16* src = qkv + (size_t)(b * S_ + s0 + row) * NQKV + 5120 + h * HD_ + cg * 8;
        *(short8*)&T[row][cg * 8] = *(const short8*)src;
    }
    __syncthreads();
    #pragma unroll
    for (int i = 0; i < 8; ++i) {
        int d = i * 16 + (tid >> 4); int cg = tid & 15;
        __align__(16) u16 tmp[8];
        #pragma unroll
        for (int j = 0; j < 8; ++j) tmp[j] = T[cg * 8 + j][d];
        *(short8*)(Vt + ((size_t)(b * NKV_ + h) * HD_ + d) * S_ + s0 + cg * 8) =
            *(short8*)tmp;
    }
}

// ---------------------------------------------------------------------------
// Flash attention v3 (unchanged; verified).
// ---------------------------------------------------------------------------
__global__ __launch_bounds__(256) void flash_attn(
    const u16* __restrict__ Q, const u16* __restrict__ Kb,
    const u16* __restrict__ Vt, u16* __restrict__ AO)
{
    const int tid  = threadIdx.x;
    const int wave = tid >> 6, lane = tid & 63;
    const int l31 = lane & 31, hi = lane >> 5;

    const int i    = blockIdx.x;
    const int xcd  = i & 7;           // blockIdx round-robins XCDs
    const int slot = i >> 3;
    const int g    = slot & 3;        // q-head within kv group
    const int qb   = 15 - ((slot >> 2) & 15);   // longest blocks first
    const int b    = slot >> 6;
    const int hk   = xcd;             // one kv head per XCD -> L2-resident
    const int h    = hk * 4 + g;
    const int qt   = qb * 4 + wave;   // 32-row q-tile index [0,64)
    const int q0   = qt * 32;
    const int qpos = q0 + l31;

    const u16* Kbase = Kb + (size_t)(b * NKV_ + hk) * S_ * HD_;
    const u16* Vbase = Vt + (size_t)(b * NKV_ + hk) * HD_ * S_;

    const u16* Qp = Q + ((size_t)(b * NH_ + h) * S_ + q0 + l31) * HD_ + hi * 8;
    short8 qf[8];
    #pragma unroll
    for (int c = 0; c < 8; ++c) qf[c] = *(const short8*)(Qp + c * 16);

    float m = -1e30f, l = 0.f;
    floatx16 o[4];
    #pragma unroll
    for (int n = 0; n < 4; ++n)
        #pragma unroll
        for (int r = 0; r < 16; ++r) o[n][r] = 0.f;

    const u16* Kp = Kbase + (size_t)l31 * HD_ + hi * 8;   // A-op: row=l31(kv)
    const u16* Vp = Vbase + (size_t)l31 * S_ + hi * 8;    // A-op: row=l31(d)

    for (int t = 0; t <= qt; ++t) {
        const int kb = t * 32;
        const u16* Kt = Kp + (size_t)kb * HD_;

        floatx16 ca, cb;
        #pragma unroll
        for (int r = 0; r < 16; ++r) { ca[r] = 0.f; cb[r] = 0.f; }
        __builtin_amdgcn_s_setprio(1);
        #pragma unroll
        for (int c = 0; c < 8; c += 2) {
            ca = __builtin_amdgcn_mfma_f32_32x32x16_bf16(
                *(const short8*)(Kt + c * 16), qf[c], ca, 0, 0, 0);
            cb = __builtin_amdgcn_mfma_f32_32x32x16_bf16(
                *(const short8*)(Kt + (c + 1) * 16), qf[c + 1], cb, 0, 0, 0);
        }
        __builtin_amdgcn_s_setprio(0);

        float s[16];
        #pragma unroll
        for (int r = 0; r < 16; ++r) s[r] = ca[r] + cb[r];

        if (t == qt) {                 // diagonal tile: causal mask
            #pragma unroll
            for (int r = 0; r < 16; ++r) {
                const int kvr = (r & 3) + 8 * (r >> 2) + 4 * hi;
                if (kb + kvr > qpos) s[r] = -1e38f;
            }
        }

        float b0 = fmaxf(fmaxf(s[0], s[1]), fmaxf(s[2], s[3]));
        float b1 = fmaxf(fmaxf(s[4], s[5]), fmaxf(s[6], s[7]));
        float b2 = fmaxf(fmaxf(s[8], s[9]), fmaxf(s[10], s[11]));
        float b3 = fmaxf(fmaxf(s[12], s[13]), fmaxf(s[14], s[15]));
        float bm = fmaxf(fmaxf(b0, b1), fmaxf(b2, b3));
        bm = fmaxf(bm, __shfl_xor(bm, 32));
        const float bmS = bm * SCALE;

        if (__any(bmS > m)) {          // rescale only when a max grew (exact)
            const float mn = fmaxf(m, bmS);
            const float al = __expf(m - mn);
            m = mn;
            l *= al;
            #pragma unroll
            for (int n = 0; n < 4; ++n)
                #pragma unroll
                for (int r = 0; r < 16; ++r) o[n][r] *= al;
        }

        float p[16];
        float rs = 0.f;
        #pragma unroll
        for (int r = 0; r < 16; ++r) {
            p[r] = __expf(fmaf(s[r], SCALE, -m));
            rs += p[r];
        }
        rs += __shfl_xor(rs, 32);
        l += rs;

        u32 P01 = (u32)f2bf(p[0])  | ((u32)f2bf(p[1])  << 16);
        u32 P23 = (u32)f2bf(p[2])  | ((u32)f2bf(p[3])  << 16);
        u32 P45 = (u32)f2bf(p[4])  | ((u32)f2bf(p[5])  << 16);
        u32 P67 = (u32)f2bf(p[6])  | ((u32)f2bf(p[7])  << 16);
        u32 P89 = (u32)f2bf(p[8])  | ((u32)f2bf(p[9])  << 16);
        u32 Pab = (u32)f2bf(p[10]) | ((u32)f2bf(p[11]) << 16);
        u32 Pcd = (u32)f2bf(p[12]) | ((u32)f2bf(p[13]) << 16);
        u32 Pef = (u32)f2bf(p[14]) | ((u32)f2bf(p[15]) << 16);
        u32 x1 = __shfl_xor(hi ? P01 : P45, 32);
        u32 x2 = __shfl_xor(hi ? P23 : P67, 32);
        u32 x3 = __shfl_xor(hi ? P89 : Pcd, 32);
        u32 x4 = __shfl_xor(hi ? Pab : Pef, 32);

        union { short8 v; u32 w[4]; } f0, f1;
        f0.w[0] = hi ? x1 : P01;  f0.w[1] = hi ? x2 : P23;
        f0.w[2] = hi ? P45 : x1;  f0.w[3] = hi ? P67 : x2;
        f1.w[0] = hi ? x3 : P89;  f1.w[1] = hi ? x4 : Pab;
        f1.w[2] = hi ? Pcd : x3;  f1.w[3] = hi ? Pef : x4;

        const u16* Vtp = Vp + kb;
        __builtin_amdgcn_s_setprio(1);
        #pragma unroll
        for (int n = 0; n < 4; ++n) {
            o[n] = __builtin_amdgcn_mfma_f32_32x32x16_bf16(
                *(const short8*)(Vtp + (size_t)(n * 32) * S_), f0.v, o[n], 0, 0, 0);
            o[n] = __builtin_amdgcn_mfma_f32_32x32x16_bf16(
                *(const short8*)(Vtp + (size_t)(n * 32) * S_ + 16), f1.v, o[n], 0, 0, 0);
        }
        __builtin_amdgcn_s_setprio(0);
    }

    const float inv = 1.0f / l;
    u16* dst = AO + ((size_t)(b * S_) + q0 + l31) * (NH_ * HD_) + h * HD_ + hi * 4;
    #pragma unroll
    for (int n = 0; n < 4; ++n)
        #pragma unroll
        for (int rg = 0; rg < 4; ++rg) {
            u32 lo  = (u32)f2bf(o[n][rg * 4 + 0] * inv) |
                      ((u32)f2bf(o[n][rg * 4 + 1] * inv) << 16);
            u32 hi2 = (u32)f2bf(o[n][rg * 4 + 2] * inv) |
                      ((u32)f2bf(o[n][rg * 4 + 3] * inv) << 16);
            *(uint2*)(dst + n * 32 + rg * 8) = make_uint2(lo, hi2);
        }
}

// ---------------------------------------------------------------------------
// Workspace layout (128 MiB total, stream-ordered reuse):
//   [0,48)    qkv_raw  -> AO (reuse [0,32)) after v_transpose
//   [48,96)   Wqkv bf16 (live only through QKV GEMM)
//             -> Qb [48,80), Kb [80,88), Vt [88,96)
//   [96,128)  hs bf16 (live through QKV GEMM) -> Wo bf16 (after flash)
// ---------------------------------------------------------------------------
extern "C" void kernel_launch(void* const* d_in, const int* in_sizes, int n_in,
                              void* d_out, int out_size, void* d_ws, size_t ws_size,
                              hipStream_t stream)
{
    const float* hs   = (const float*)d_in[0];
    const float* cosp = (const float*)d_in[1];
    const float* sinp = (const float*)d_in[2];
    const float* wq   = (const float*)d_in[3];
    const float* wk   = (const float*)d_in[4];
    const float* wv   = (const float*)d_in[5];
    const float* wo   = (const float*)d_in[6];
    float* out = (float*)d_out;
    char* ws = (char*)d_ws;

    const size_t MB = 1024 * 1024;
    u16* qkv_raw = (u16*)ws;                      // 48 MiB
    u16* AO      = (u16*)ws;                      // 32 MiB (reuse)
    u16* Wqkv    = (u16*)(ws + 48 * MB);          // 48 MiB (transient)
    u16* Qb      = (u16*)(ws + 48 * MB);          // 32 MiB (after QKV GEMM)
    u16* Kb      = (u16*)(ws + 80 * MB);          //  8 MiB
    u16* Vt      = (u16*)(ws + 88 * MB);          //  8 MiB
    u16* hs_bf   = (u16*)(ws + 96 * MB);          // 32 MiB
    u16* Wo_bf   = (u16*)(ws + 96 * MB);          // 32 MiB (after flash)

    // one-time f32 -> bf16 conversions
    cvt_bf16<<<8192, 256, 0, stream>>>(hs, hs_bf, (M_TOK * D_) / 8);
    cvt_bf16<<<8192, 256, 0, stream>>>(wq, Wqkv, (NH_ * HD_ * D_) / 8);
    cvt_bf16<<<2048, 256, 0, stream>>>(wk, Wqkv + (size_t)NH_ * HD_ * D_, (NKV_ * HD_ * D_) / 8);
    cvt_bf16<<<2048, 256, 0, stream>>>(wv, Wqkv + (size_t)(NH_ + NKV_) * HD_ * D_, (NKV_ * HD_ * D_) / 8);

    // QKV GEMM: M=4096, N=6144, K=4096 -> grid 48x16 = 768 blocks (3 rounds)
    gemm_pipe<false><<<dim3(NQKV / 128, M_TOK / 256), 512, 0, stream>>>(
        hs_bf, Wqkv, qkv_raw, M_TOK, NQKV, D_);

    rope_reshape<<<40960, 256, 0, stream>>>(qkv_raw, cosp, sinp, Qb, Kb);

    v_transpose<<<256, 256, 0, stream>>>(qkv_raw, Vt);

    flash_attn<<<1024, 256, 0, stream>>>(Qb, Kb, Vt, AO);

    cvt_bf16<<<8192, 256, 0, stream>>>(wo, Wo_bf, (D_ * NH_ * HD_) / 8);

    // WO GEMM: M=4096, N=4096, K=4096 -> grid 32x16 = 512 blocks (2 rounds)
    gemm_pipe<true><<<dim3(D_ / 128, M_TOK / 256), 512, 0, stream>>>(
        AO, Wo_bf, out, M_TOK, D_, NH_ * HD_);
}

// Round 5
// 785.859 us; speedup vs baseline: 1.8221x; 1.1225x over previous
//
#include <hip/hip_runtime.h>

#define B_    2
#define S_    2048
#define D_    4096
#define NH_   32
#define NKV_  8
#define HD_   128
#define M_TOK 4096           // B_*S_
#define NQKV  6144           // (NH_+2*NKV_)*HD_
#define SCALE 0.08838834764831845f

typedef unsigned short u16;
typedef unsigned int   u32;
typedef __attribute__((ext_vector_type(8))) short short8;
typedef __attribute__((ext_vector_type(4))) float floatx4;
typedef __attribute__((ext_vector_type(16))) float floatx16;

typedef const __attribute__((address_space(1))) void cg_void;
typedef __attribute__((address_space(3))) void lds_void;
#define GP(x) ((cg_void*)(x))
#define LP(x) ((lds_void*)(x))

__device__ inline u16 f2bf(float f) {
    u32 u = __float_as_uint(f);
    u = (u + 0x7FFFu + ((u >> 16) & 1u)) >> 16;
    return (u16)u;
}
__device__ inline float bf2f(u16 u) {
    return __uint_as_float(((u32)u) << 16);
}
__device__ inline u32 cvt_pk_bf16(float a, float b) {   // {lo=bf16(a), hi=bf16(b)}, RNE
    u32 r;
    asm("v_cvt_pk_bf16_f32 %0, %1, %2" : "=v"(r) : "v"(a), "v"(b));
    return r;
}

// ---------------------------------------------------------------------------
// f32 -> bf16 streaming converter (unchanged).
// ---------------------------------------------------------------------------
__global__ __launch_bounds__(256) void cvt_bf16(
    const float* __restrict__ src, u16* __restrict__ dst, int n8)
{
    int id = blockIdx.x * 256 + threadIdx.x;
    if (id >= n8) return;
    size_t i = (size_t)id * 8;
    float4 a = *(const float4*)(src + i);
    float4 b = *(const float4*)(src + i + 4);
    __align__(16) u16 t[8];
    t[0] = f2bf(a.x); t[1] = f2bf(a.y); t[2] = f2bf(a.z); t[3] = f2bf(a.w);
    t[4] = f2bf(b.x); t[5] = f2bf(b.y); t[6] = f2bf(b.z); t[7] = f2bf(b.w);
    *(short8*)(dst + i) = *(short8*)t;
}

// ---------------------------------------------------------------------------
// Deep-pipelined bf16 B^T GEMM (unchanged from round 4; verified).
// ---------------------------------------------------------------------------
#define GBK 64
#define A_U16 (256 * GBK)      // 16384 u16 = 32 KiB
#define B_U16 (128 * GBK)      //  8192 u16 = 16 KiB
#define BUF_U16 (A_U16 + B_U16)

template<bool OUT_F32>
__global__ __launch_bounds__(512) void gemm_pipe(
    const u16* __restrict__ A, const u16* __restrict__ Bw,
    void* __restrict__ Cp, int M, int N, int K)
{
    __shared__ __align__(16) u16 smem[2][BUF_U16];   // 96 KiB

    const int tid  = threadIdx.x;
    const int lane = tid & 63, wave = tid >> 6;
    const int quad = lane >> 4, l16 = lane & 15;

    const int gx  = gridDim.x;
    const int lin = blockIdx.y * gx + blockIdx.x;
    const int nwg = gx * gridDim.y;
    const int wg  = (lin & 7) * (nwg >> 3) + (lin >> 3);
    const int by  = wg / gx, bx = wg - by * gx;
    const int m0 = by * 256, n0 = bx * 128;

    const int wm = (wave >> 1) * 64;   // 4 M-waves
    const int wn = (wave & 1) * 64;    // 2 N-waves

    const int srow  = tid >> 3;
    const int sslot = tid & 7;
    const u16* Asrc = A  + (size_t)(m0 + srow) * K + (size_t)((sslot ^ (srow & 7)) * 8);
    const u16* Bsrc = Bw + (size_t)(n0 + srow) * K + (size_t)((sslot ^ (srow & 7)) * 8);

    const int NT = K / GBK;
    const int sw = l16 & 7;

    floatx4 acc[4][4];
    #pragma unroll
    for (int i = 0; i < 4; ++i)
        #pragma unroll
        for (int j = 0; j < 4; ++j) acc[i][j] = (floatx4){0.f, 0.f, 0.f, 0.f};

    #pragma unroll
    for (int tb = 0; tb < 2; ++tb) {
        u16* Ad = &smem[tb][0]     + tid * 8;
        u16* Bd = &smem[tb][A_U16] + tid * 8;
        const size_t k0 = (size_t)tb * GBK;
        #pragma unroll
        for (int q = 0; q < 4; ++q)
            __builtin_amdgcn_global_load_lds(GP(Asrc + (size_t)q * 64 * K + k0),
                                             LP(Ad + q * 4096), 16, 0, 0);
        #pragma unroll
        for (int q = 0; q < 2; ++q)
            __builtin_amdgcn_global_load_lds(GP(Bsrc + (size_t)q * 64 * K + k0),
                                             LP(Bd + q * 4096), 16, 0, 0);
    }
    __builtin_amdgcn_sched_barrier(0);
    asm volatile("s_waitcnt vmcnt(6)" ::: "memory");
    __builtin_amdgcn_sched_barrier(0);
    __builtin_amdgcn_s_barrier();

    #pragma unroll 1
    for (int t = 0; t < NT; ++t) {
        const u16* Ab = &smem[t & 1][0]     + (size_t)(wm + l16) * GBK;
        const u16* Bb = &smem[t & 1][A_U16] + (size_t)(wn + l16) * GBK;

        #pragma unroll
        for (int kh = 0; kh < 2; ++kh) {
            const int sl = ((kh * 4 + quad) ^ sw) * 8;
            short8 af[4], bfv[4];
            #pragma unroll
            for (int i = 0; i < 4; ++i)
                af[i] = *(const short8*)(Ab + i * 16 * GBK + sl);
            #pragma unroll
            for (int j = 0; j < 4; ++j)
                bfv[j] = *(const short8*)(Bb + j * 16 * GBK + sl);

            __builtin_amdgcn_s_barrier();
            __builtin_amdgcn_s_setprio(1);
            #pragma unroll
            for (int i = 0; i < 4; ++i)
                #pragma unroll
                for (int j = 0; j < 4; ++j)
                    acc[i][j] = __builtin_amdgcn_mfma_f32_16x16x32_bf16(
                        af[i], bfv[j], acc[i][j], 0, 0, 0);
            __builtin_amdgcn_s_setprio(0);
            __builtin_amdgcn_s_barrier();
        }

        if (t + 1 == NT) break;

        __builtin_amdgcn_sched_barrier(0);
        if (t + 2 < NT) {
            u16* Ad = &smem[t & 1][0]     + tid * 8;
            u16* Bd = &smem[t & 1][A_U16] + tid * 8;
            const size_t k0 = (size_t)(t + 2) * GBK;
            #pragma unroll
            for (int q = 0; q < 4; ++q)
                __builtin_amdgcn_global_load_lds(GP(Asrc + (size_t)q * 64 * K + k0),
                                                 LP(Ad + q * 4096), 16, 0, 0);
            #pragma unroll
            for (int q = 0; q < 2; ++q)
                __builtin_amdgcn_global_load_lds(GP(Bsrc + (size_t)q * 64 * K + k0),
                                                 LP(Bd + q * 4096), 16, 0, 0);
            __builtin_amdgcn_sched_barrier(0);
            asm volatile("s_waitcnt vmcnt(6)" ::: "memory");
        } else {
            asm volatile("s_waitcnt vmcnt(0)" ::: "memory");
        }
        __builtin_amdgcn_sched_barrier(0);
        __builtin_amdgcn_s_barrier();
    }

    #pragma unroll
    for (int i = 0; i < 4; ++i)
        #pragma unroll
        for (int j = 0; j < 4; ++j)
            #pragma unroll
            for (int r = 0; r < 4; ++r) {
                int row = m0 + wm + i * 16 + quad * 4 + r;
                int col = n0 + wn + j * 16 + l16;
                float v = acc[i][j][r];
                if constexpr (OUT_F32)
                    ((float*)Cp)[(size_t)row * N + col] = v;
                else
                    ((u16*)Cp)[(size_t)row * N + col] = f2bf(v);
            }
}

// ---------------------------------------------------------------------------
// RoPE + head-major reshape for Q and K (unchanged).
// ---------------------------------------------------------------------------
__global__ __launch_bounds__(256) void rope_reshape(
    const u16* __restrict__ qkv, const float* __restrict__ cosp,
    const float* __restrict__ sinp, u16* __restrict__ Q, u16* __restrict__ Kb)
{
    const size_t QN = (size_t)M_TOK * NH_ * 64;
    size_t id = (size_t)blockIdx.x * 256 + threadIdx.x;
    if (id < QN) {
        int j = id & 63; int h = (id >> 6) & (NH_ - 1); int tok = (int)(id >> 11);
        int b = tok >> 11, s = tok & (S_ - 1);
        float c  = cosp[(size_t)tok * HD_ + j];
        float sn = sinp[(size_t)tok * HD_ + j];
        float x1 = bf2f(qkv[(size_t)tok * NQKV + h * HD_ + j]);
        float x2 = bf2f(qkv[(size_t)tok * NQKV + h * HD_ + 64 + j]);
        size_t o = ((size_t)(b * NH_ + h) * S_ + s) * HD_ + j;
        Q[o]      = f2bf(x1 * c - x2 * sn);
        Q[o + 64] = f2bf(x2 * c + x1 * sn);
    } else {
        size_t kid = id - QN;
        int j = kid & 63; int h = (kid >> 6) & (NKV_ - 1); int tok = (int)(kid >> 9);
        int b = tok >> 11, s = tok & (S_ - 1);
        float c  = cosp[(size_t)tok * HD_ + j];
        float sn = sinp[(size_t)tok * HD_ + j];
        float x1 = bf2f(qkv[(size_t)tok * NQKV + 4096 + h * HD_ + j]);
        float x2 = bf2f(qkv[(size_t)tok * NQKV + 4096 + h * HD_ + 64 + j]);
        size_t o = ((size_t)(b * NKV_ + h) * S_ + s) * HD_ + j;
        Kb[o]      = f2bf(x1 * c - x2 * sn);
        Kb[o + 64] = f2bf(x2 * c + x1 * sn);
    }
}

// ---------------------------------------------------------------------------
// V transpose (unchanged): qkv V part -> Vt[b,hk,d,s]
// ---------------------------------------------------------------------------
__global__ __launch_bounds__(256) void v_transpose(
    const u16* __restrict__ qkv, u16* __restrict__ Vt)
{
    __shared__ __align__(16) u16 T[128][136];
    int bidx = blockIdx.x;
    int st = bidx & 15; int h = (bidx >> 4) & 7; int b = bidx >> 7;
    int s0 = st * 128;
    int tid = threadIdx.x;
    #pragma unroll
    for (int i = 0; i < 8; ++i) {
        int row = i * 16 + (tid >> 4); int cg = tid & 15;
        const u16* src = qkv + (size_t)(b * S_ + s0 + row) * NQKV + 5120 + h * HD_ + cg * 8;
        *(short8*)&T[row][cg * 8] = *(const short8*)src;
    }
    __syncthreads();
    #pragma unroll
    for (int i = 0; i < 8; ++i) {
        int d = i * 16 + (tid >> 4); int cg = tid & 15;
        __align__(16) u16 tmp[8];
        #pragma unroll
        for (int j = 0; j < 8; ++j) tmp[j] = T[cg * 8 + j][d];
        *(short8*)(Vt + ((size_t)(b * NKV_ + h) * HD_ + d) * S_ + s0 + cg * 8) =
            *(short8*)tmp;
    }
}

// ---------------------------------------------------------------------------
// Flash attention v4.  Changes vs v3:
//  * K/V tiles staged in LDS (double-buffered 32 KiB) via global_load_lds,
//    counted s_waitcnt vmcnt(4): next tile's loads stay in flight across the
//    whole current tile -> global latency off the critical path.  The 4
//    waves of a block share one (b,hk) -> 4x L2 read-traffic reduction.
//  * Conflict-free LDS layouts via per-lane SOURCE permutation (LDS dest is
//    lane-linear as required): K stored as [dslot 16][kv 32] granules,
//    V as [kvslot 4][d 128] granules -> every ds_read_b128 is lane-
//    consecutive stride-1 (0 bank conflicts).
//  * P-pack and epilogue use v_cvt_pk_bf16_f32 (8 instrs vs ~64 int ops).
//  * Block iterates lockstep over TB=4*qb+4 tiles; waves skip compute for
//    t>qt (<=3 idle tiles); barrier counts uniform.
// ---------------------------------------------------------------------------
__global__ __launch_bounds__(256) void flash_attn(
    const u16* __restrict__ Q, const u16* __restrict__ Kb,
    const u16* __restrict__ Vt, u16* __restrict__ AO)
{
    __shared__ __align__(16) u16 smem[2][8192];   // [buf][K 8KB | V 8KB]

    const int tid  = threadIdx.x;
    const int wave = tid >> 6, lane = tid & 63;
    const int l31 = lane & 31, hi = lane >> 5;

    const int i    = blockIdx.x;
    const int xcd  = i & 7;
    const int slot = i >> 3;
    const int g    = slot & 3;
    const int qb   = 15 - ((slot >> 2) & 15);   // longest blocks first
    const int b    = slot >> 6;
    const int hk   = xcd;
    const int h    = hk * 4 + g;
    const int qt   = qb * 4 + wave;             // this wave's q-tile
    const int q0   = qt * 32;
    const int qpos = q0 + l31;
    const int TB   = qb * 4 + 4;                // tiles processed per block

    const u16* Kbase = Kb + (size_t)(b * NKV_ + hk) * S_ * HD_;
    const u16* Vbase = Vt + (size_t)(b * NKV_ + hk) * HD_ * S_;

    // Q fragments (global, once); drain before manual vmcnt accounting
    const u16* Qp = Q + ((size_t)(b * NH_ + h) * S_ + q0 + l31) * HD_ + hi * 8;
    short8 qf[8];
    #pragma unroll
    for (int c = 0; c < 8; ++c) qf[c] = *(const short8*)(Qp + c * 16);
    __builtin_amdgcn_sched_barrier(0);
    asm volatile("s_waitcnt vmcnt(0)" ::: "memory");
    __builtin_amdgcn_sched_barrier(0);

    // staging: granule g16 in [0,512) per region, dest lane-linear.
    //   K: g16 = dslot*32 + kv  -> src col dslot*8 of row (kb+kv)
    //   V: g16 = kvslot*128 + d -> src col kb+kvslot*8 of row d
    const int gk0 = tid, gk1 = tid + 256;
    const int kdsl0 = gk0 >> 5, kkv0 = gk0 & 31;
    const int kdsl1 = gk1 >> 5, kkv1 = gk1 & 31;
    const int vks0 = gk0 >> 7, vd0 = gk0 & 127;
    const int vks1 = gk1 >> 7, vd1 = gk1 & 127;

    #define STAGE_KV(kb_, buf_)                                                        \
        do {                                                                           \
            u16* Ksd = &smem[buf_][0];                                                 \
            u16* Vsd = &smem[buf_][4096];                                              \
            __builtin_amdgcn_global_load_lds(                                          \
                GP(Kbase + (size_t)((kb_) + kkv0) * HD_ + kdsl0 * 8),                  \
                LP(Ksd + gk0 * 8), 16, 0, 0);                                          \
            __builtin_amdgcn_global_load_lds(                                          \
                GP(Kbase + (size_t)((kb_) + kkv1) * HD_ + kdsl1 * 8),                  \
                LP(Ksd + gk1 * 8), 16, 0, 0);                                          \
            __builtin_amdgcn_global_load_lds(                                          \
                GP(Vbase + (size_t)vd0 * S_ + (kb_) + vks0 * 8),                       \
                LP(Vsd + gk0 * 8), 16, 0, 0);                                          \
            __builtin_amdgcn_global_load_lds(                                          \
                GP(Vbase + (size_t)vd1 * S_ + (kb_) + vks1 * 8),                       \
                LP(Vsd + gk1 * 8), 16, 0, 0);                                          \
        } while (0)

    float m = -1e30f, l = 0.f;
    floatx16 o[4];
    #pragma unroll
    for (int n = 0; n < 4; ++n)
        #pragma unroll
        for (int r = 0; r < 16; ++r) o[n][r] = 0.f;

    // prologue: stage tiles 0 and 1 (TB >= 4 always)
    STAGE_KV(0, 0);
    STAGE_KV(32, 1);
    __builtin_amdgcn_sched_barrier(0);
    asm volatile("s_waitcnt vmcnt(4)" ::: "memory");
    __builtin_amdgcn_sched_barrier(0);
    __builtin_amdgcn_s_barrier();

    #pragma unroll 1
    for (int t = 0; t < TB; ++t) {
        const u16* Ks = &smem[t & 1][0];
        const u16* Vs = &smem[t & 1][4096];

        if (t <= qt) {
            const int kb = t * 32;

            // S^T[kv][q]: K from LDS (granule (2c+hi)*32 + l31), 2 acc chains
            floatx16 ca, cb;
            #pragma unroll
            for (int r = 0; r < 16; ++r) { ca[r] = 0.f; cb[r] = 0.f; }
            __builtin_amdgcn_s_setprio(1);
            #pragma unroll
            for (int c = 0; c < 8; c += 2) {
                ca = __builtin_amdgcn_mfma_f32_32x32x16_bf16(
                    *(const short8*)(Ks + (2 * c + hi) * 256 + l31 * 8),
                    qf[c], ca, 0, 0, 0);
                cb = __builtin_amdgcn_mfma_f32_32x32x16_bf16(
                    *(const short8*)(Ks + (2 * (c + 1) + hi) * 256 + l31 * 8),
                    qf[c + 1], cb, 0, 0, 0);
            }
            __builtin_amdgcn_s_setprio(0);

            float s[16];
            #pragma unroll
            for (int r = 0; r < 16; ++r) s[r] = ca[r] + cb[r];

            if (t == qt) {             // diagonal tile: causal mask
                #pragma unroll
                for (int r = 0; r < 16; ++r) {
                    const int kvr = (r & 3) + 8 * (r >> 2) + 4 * hi;
                    if (kb + kvr > qpos) s[r] = -1e38f;
                }
            }

            float b0 = fmaxf(fmaxf(s[0], s[1]), fmaxf(s[2], s[3]));
            float b1 = fmaxf(fmaxf(s[4], s[5]), fmaxf(s[6], s[7]));
            float b2 = fmaxf(fmaxf(s[8], s[9]), fmaxf(s[10], s[11]));
            float b3 = fmaxf(fmaxf(s[12], s[13]), fmaxf(s[14], s[15]));
            float bm = fmaxf(fmaxf(b0, b1), fmaxf(b2, b3));
            bm = fmaxf(bm, __shfl_xor(bm, 32));
            const float bmS = bm * SCALE;

            if (__any(bmS > m)) {      // rescale only when a max grew (exact)
                const float mn = fmaxf(m, bmS);
                const float al = __expf(m - mn);
                m = mn;
                l *= al;
                #pragma unroll
                for (int n = 0; n < 4; ++n)
                    #pragma unroll
                    for (int r = 0; r < 16; ++r) o[n][r] *= al;
            }

            float p[16];
            float rs = 0.f;
            #pragma unroll
            for (int r = 0; r < 16; ++r) {
                p[r] = __expf(fmaf(s[r], SCALE, -m));
                rs += p[r];
            }
            rs += __shfl_xor(rs, 32);
            l += rs;

            // P^T B-fragments: 8 cvt_pk + 4 xor-32 shuffles + selects
            u32 P01 = cvt_pk_bf16(p[0],  p[1]);
            u32 P23 = cvt_pk_bf16(p[2],  p[3]);
            u32 P45 = cvt_pk_bf16(p[4],  p[5]);
            u32 P67 = cvt_pk_bf16(p[6],  p[7]);
            u32 P89 = cvt_pk_bf16(p[8],  p[9]);
            u32 Pab = cvt_pk_bf16(p[10], p[11]);
            u32 Pcd = cvt_pk_bf16(p[12], p[13]);
            u32 Pef = cvt_pk_bf16(p[14], p[15]);
            u32 x1 = __shfl_xor(hi ? P01 : P45, 32);
            u32 x2 = __shfl_xor(hi ? P23 : P67, 32);
            u32 x3 = __shfl_xor(hi ? P89 : Pcd, 32);
            u32 x4 = __shfl_xor(hi ? Pab : Pef, 32);

            union { short8 v; u32 w[4]; } f0, f1;
            f0.w[0] = hi ? x1 : P01;  f0.w[1] = hi ? x2 : P23;
            f0.w[2] = hi ? P45 : x1;  f0.w[3] = hi ? P67 : x2;
            f1.w[0] = hi ? x3 : P89;  f1.w[1] = hi ? x4 : Pab;
            f1.w[2] = hi ? Pcd : x3;  f1.w[3] = hi ? Pef : x4;

            // O^T[d][q] += V^T[d][kv] * P^T[kv][q]; V from LDS
            __builtin_amdgcn_s_setprio(1);
            #pragma unroll
            for (int n = 0; n < 4; ++n) {
                o[n] = __builtin_amdgcn_mfma_f32_32x32x16_bf16(
                    *(const short8*)(Vs + (hi) * 1024 + (n * 32 + l31) * 8),
                    f0.v, o[n], 0, 0, 0);
                o[n] = __builtin_amdgcn_mfma_f32_32x32x16_bf16(
                    *(const short8*)(Vs + (2 + hi) * 1024 + (n * 32 + l31) * 8),
                    f1.v, o[n], 0, 0, 0);
            }
            __builtin_amdgcn_s_setprio(0);
        }

        __builtin_amdgcn_s_barrier();          // all waves done with buf[t&1]
        __builtin_amdgcn_sched_barrier(0);
        if (t + 2 < TB) {
            STAGE_KV((t + 2) * 32, t & 1);     // refill just-freed buffer
            __builtin_amdgcn_sched_barrier(0);
            asm volatile("s_waitcnt vmcnt(4)" ::: "memory");   // t+1 resident
        } else if (t + 1 < TB) {
            asm volatile("s_waitcnt vmcnt(0)" ::: "memory");
        }
        __builtin_amdgcn_sched_barrier(0);
        __builtin_amdgcn_s_barrier();
    }
    #undef STAGE_KV

    // epilogue: lane holds O^T[d = n*32 + (r&3)+8*(r>>2)+4*hi][q = l31]
    const float inv = 1.0f / l;
    u16* dst = AO + ((size_t)(b * S_) + q0 + l31) * (NH_ * HD_) + h * HD_ + hi * 4;
    #pragma unroll
    for (int n = 0; n < 4; ++n)
        #pragma unroll
        for (int rg = 0; rg < 4; ++rg) {
            u32 lo  = cvt_pk_bf16(o[n][rg * 4 + 0] * inv, o[n][rg * 4 + 1] * inv);
            u32 hi2 = cvt_pk_bf16(o[n][rg * 4 + 2] * inv, o[n][rg * 4 + 3] * inv);
            *(uint2*)(dst + n * 32 + rg * 8) = make_uint2(lo, hi2);
        }
}

// ---------------------------------------------------------------------------
// Workspace layout (128 MiB total, stream-ordered reuse):
//   [0,48)    qkv_raw  -> AO (reuse [0,32)) after v_transpose
//   [48,96)   Wqkv bf16 (live only through QKV GEMM)
//             -> Qb [48,80), Kb [80,88), Vt [88,96)
//   [96,128)  hs bf16 (live through QKV GEMM) -> Wo bf16 (after flash)
// ---------------------------------------------------------------------------
extern "C" void kernel_launch(void* const* d_in, const int* in_sizes, int n_in,
                              void* d_out, int out_size, void* d_ws, size_t ws_size,
                              hipStream_t stream)
{
    const float* hs   = (const float*)d_in[0];
    const float* cosp = (const float*)d_in[1];
    const float* sinp = (const float*)d_in[2];
    const float* wq   = (const float*)d_in[3];
    const float* wk   = (const float*)d_in[4];
    const float* wv   = (const float*)d_in[5];
    const float* wo   = (const float*)d_in[6];
    float* out = (float*)d_out;
    char* ws = (char*)d_ws;

    const size_t MB = 1024 * 1024;
    u16* qkv_raw = (u16*)ws;                      // 48 MiB
    u16* AO      = (u16*)ws;                      // 32 MiB (reuse)
    u16* Wqkv    = (u16*)(ws + 48 * MB);          // 48 MiB (transient)
    u16* Qb      = (u16*)(ws + 48 * MB);          // 32 MiB (after QKV GEMM)
    u16* Kb      = (u16*)(ws + 80 * MB);          //  8 MiB
    u16* Vt      = (u16*)(ws + 88 * MB);          //  8 MiB
    u16* hs_bf   = (u16*)(ws + 96 * MB);          // 32 MiB
    u16* Wo_bf   = (u16*)(ws + 96 * MB);          // 32 MiB (after flash)

    cvt_bf16<<<8192, 256, 0, stream>>>(hs, hs_bf, (M_TOK * D_) / 8);
    cvt_bf16<<<8192, 256, 0, stream>>>(wq, Wqkv, (NH_ * HD_ * D_) / 8);
    cvt_bf16<<<2048, 256, 0, stream>>>(wk, Wqkv + (size_t)NH_ * HD_ * D_, (NKV_ * HD_ * D_) / 8);
    cvt_bf16<<<2048, 256, 0, stream>>>(wv, Wqkv + (size_t)(NH_ + NKV_) * HD_ * D_, (NKV_ * HD_ * D_) / 8);

    gemm_pipe<false><<<dim3(NQKV / 128, M_TOK / 256), 512, 0, stream>>>(
        hs_bf, Wqkv, qkv_raw, M_TOK, NQKV, D_);

    rope_reshape<<<40960, 256, 0, stream>>>(qkv_raw, cosp, sinp, Qb, Kb);

    v_transpose<<<256, 256, 0, stream>>>(qkv_raw, Vt);

    flash_attn<<<1024, 256, 0, stream>>>(Qb, Kb, Vt, AO);

    cvt_bf16<<<8192, 256, 0, stream>>>(wo, Wo_bf, (D_ * NH_ * HD_) / 8);

    gemm_pipe<true><<<dim3(D_ / 128, M_TOK / 256), 512, 0, stream>>>(
        AO, Wo_bf, out, M_TOK, D_, NH_ * HD_);
}

// Round 6
// 732.412 us; speedup vs baseline: 1.9550x; 1.0730x over previous
//
#include <hip/hip_runtime.h>

#define B_    2
#define S_    2048
#define D_    4096
#define NH_   32
#define NKV_  8
#define HD_   128
#define M_TOK 4096           // B_*S_
#define NQKV  6144           // (NH_+2*NKV_)*HD_
#define SCALE 0.08838834764831845f

typedef unsigned short u16;
typedef unsigned int   u32;
typedef __attribute__((ext_vector_type(8))) short short8;
typedef __attribute__((ext_vector_type(4))) float floatx4;
typedef __attribute__((ext_vector_type(16))) float floatx16;

typedef const __attribute__((address_space(1))) void cg_void;
typedef __attribute__((address_space(3))) void lds_void;
#define GP(x) ((cg_void*)(x))
#define LP(x) ((lds_void*)(x))

__device__ inline u16 f2bf(float f) {
    u32 u = __float_as_uint(f);
    u = (u + 0x7FFFu + ((u >> 16) & 1u)) >> 16;
    return (u16)u;
}
__device__ inline float bf2f(u16 u) {
    return __uint_as_float(((u32)u) << 16);
}
__device__ inline u32 cvt_pk_bf16(float a, float b) {   // {lo=bf16(a), hi=bf16(b)}, RNE
    u32 r;
    asm("v_cvt_pk_bf16_f32 %0, %1, %2" : "=v"(r) : "v"(a), "v"(b));
    return r;
}

// ---------------------------------------------------------------------------
// f32 -> bf16 streaming converter (unchanged).
// ---------------------------------------------------------------------------
__global__ __launch_bounds__(256) void cvt_bf16(
    const float* __restrict__ src, u16* __restrict__ dst, int n8)
{
    int id = blockIdx.x * 256 + threadIdx.x;
    if (id >= n8) return;
    size_t i = (size_t)id * 8;
    float4 a = *(const float4*)(src + i);
    float4 b = *(const float4*)(src + i + 4);
    __align__(16) u16 t[8];
    t[0] = f2bf(a.x); t[1] = f2bf(a.y); t[2] = f2bf(a.z); t[3] = f2bf(a.w);
    t[4] = f2bf(b.x); t[5] = f2bf(b.y); t[6] = f2bf(b.z); t[7] = f2bf(b.w);
    *(short8*)(dst + i) = *(short8*)t;
}

// ---------------------------------------------------------------------------
// Deep-pipelined bf16 B^T GEMM v2:  C[m,n] = sum_k A[m,k] * B[n,k].
// BM=256 BN=256 BK=64, 512 threads = 8 waves (2M x 4N), 128x64 per wave
// (acc[8][4] -> 42.7 FLOP per LDS byte vs 32 for 64x64; LDS no longer
// co-dominant with MFMA).
// - barriers ONLY at tile boundaries (dbuf LDS -> no intra-tile hazard);
//   compiler free to pipeline the 24 ds_reads into the 64 MFMAs, and the
//   2 waves/SIMD skew within a tile -> ds_read overlaps MFMA.
// - double-buffered 128 KiB LDS; stage tile t+2 at the boundary of tile t;
//   counted s_waitcnt vmcnt(8) (never drained in the main loop).
// - LDS XOR swizzle (slot ^= row&7) on global SOURCE address + ds_read
//   address (linear global_load_lds dest) -> conflict-free b128 both sides.
// - bijective XCD-chunked block swizzle (384 / 256 blocks, both % 8 == 0).
// ---------------------------------------------------------------------------
#define GBK 64
#define TA_U16 (256 * GBK)     // 16384 u16 = 32 KiB
#define TB_U16 (256 * GBK)     // 16384 u16 = 32 KiB
#define TBUF_U16 (TA_U16 + TB_U16)

template<bool OUT_F32>
__global__ __launch_bounds__(512) void gemm_pipe(
    const u16* __restrict__ A, const u16* __restrict__ Bw,
    void* __restrict__ Cp, int M, int N, int K)
{
    __shared__ __align__(16) u16 smem[2][TBUF_U16];   // 128 KiB

    const int tid  = threadIdx.x;
    const int lane = tid & 63, wave = tid >> 6;
    const int quad = lane >> 4, l16 = lane & 15;

    // bijective XCD-chunked swizzle (nwg % 8 == 0 at both call sites)
    const int gx  = gridDim.x;
    const int lin = blockIdx.y * gx + blockIdx.x;
    const int nwg = gx * gridDim.y;
    const int wg  = (lin & 7) * (nwg >> 3) + (lin >> 3);
    const int by  = wg / gx, bx = wg - by * gx;
    const int m0 = by * 256, n0 = bx * 256;

    const int wr = wave >> 2;          // 0..1 : 128-row M-half
    const int wc = wave & 3;           // 0..3 : 64-col N-quarter

    const int NT = K / GBK;
    const int sw = l16 & 7;            // fragment read swizzle

    // staging: granule g in [0,2048) per region; row = g>>3, slot = g&7;
    // LDS dest lane-linear (g*16B); swizzle on the global source column.
    #define STAGE(t_, buf_)                                                          \
        do {                                                                         \
            const size_t kk_ = (size_t)(t_) * GBK;                                   \
            _Pragma("unroll")                                                        \
            for (int q = 0; q < 4; ++q) {                                            \
                const int g_ = q * 512 + tid;                                        \
                const int r_ = g_ >> 3, s_ = g_ & 7;                                 \
                __builtin_amdgcn_global_load_lds(                                    \
                    GP(A + (size_t)(m0 + r_) * K + kk_ + ((s_ ^ (r_ & 7)) * 8)),     \
                    LP(&smem[buf_][0] + (size_t)g_ * 8), 16, 0, 0);                  \
            }                                                                        \
            _Pragma("unroll")                                                        \
            for (int q = 0; q < 4; ++q) {                                            \
                const int g_ = q * 512 + tid;                                        \
                const int r_ = g_ >> 3, s_ = g_ & 7;                                 \
                __builtin_amdgcn_global_load_lds(                                    \
                    GP(Bw + (size_t)(n0 + r_) * K + kk_ + ((s_ ^ (r_ & 7)) * 8)),    \
                    LP(&smem[buf_][TA_U16] + (size_t)g_ * 8), 16, 0, 0);             \
            }                                                                        \
        } while (0)

    floatx4 acc[8][4];
    #pragma unroll
    for (int i = 0; i < 8; ++i)
        #pragma unroll
        for (int j = 0; j < 4; ++j) acc[i][j] = (floatx4){0.f, 0.f, 0.f, 0.f};

    // per-thread read bases (u16 units): granule = row*8 + p, offset = g*8
    const int abase = (wr * 128 + l16) * 64;            // + m*1024 + p*8
    const int bbase = TA_U16 + (wc * 64 + l16) * 64;    // + n*1024 + p*8

    // prologue: stage tiles 0 and 1; wait for tile 0 (8 loads left in flight)
    STAGE(0, 0);
    STAGE(1, 1);
    __builtin_amdgcn_sched_barrier(0);
    asm volatile("s_waitcnt vmcnt(8)" ::: "memory");
    __builtin_amdgcn_sched_barrier(0);
    __builtin_amdgcn_s_barrier();

    #pragma unroll 1
    for (int t = 0; t < NT; ++t) {
        const u16* Sb = &smem[t & 1][0];

        #pragma unroll
        for (int kh = 0; kh < 2; ++kh) {
            const int p = ((kh * 4 + quad) ^ sw) * 8;
            short8 af[8], bfv[4];
            #pragma unroll
            for (int m = 0; m < 8; ++m)
                af[m] = *(const short8*)(Sb + abase + m * 1024 + p);
            #pragma unroll
            for (int n = 0; n < 4; ++n)
                bfv[n] = *(const short8*)(Sb + bbase + n * 1024 + p);
            #pragma unroll
            for (int m = 0; m < 8; ++m)
                #pragma unroll
                for (int n = 0; n < 4; ++n)
                    acc[m][n] = __builtin_amdgcn_mfma_f32_16x16x32_bf16(
                        af[m], bfv[n], acc[m][n], 0, 0, 0);
        }

        __builtin_amdgcn_s_barrier();          // all waves done with buf[t&1]
        __builtin_amdgcn_sched_barrier(0);
        if (t + 2 < NT) {
            STAGE(t + 2, t & 1);               // refill just-freed buffer
            __builtin_amdgcn_sched_barrier(0);
            asm volatile("s_waitcnt vmcnt(8)" ::: "memory");   // t+1 resident
        } else if (t + 1 < NT) {
            asm volatile("s_waitcnt vmcnt(0)" ::: "memory");
        }
        __builtin_amdgcn_sched_barrier(0);
        __builtin_amdgcn_s_barrier();
    }
    #undef STAGE

    #pragma unroll
    for (int m = 0; m < 8; ++m)
        #pragma unroll
        for (int n = 0; n < 4; ++n)
            #pragma unroll
            for (int r = 0; r < 4; ++r) {
                int row = m0 + wr * 128 + m * 16 + quad * 4 + r;
                int col = n0 + wc * 64 + n * 16 + l16;
                float v = acc[m][n][r];
                if constexpr (OUT_F32)
                    ((float*)Cp)[(size_t)row * N + col] = v;
                else
                    ((u16*)Cp)[(size_t)row * N + col] = f2bf(v);
            }
}

// ---------------------------------------------------------------------------
// RoPE + head-major reshape for Q and K (unchanged).
// ---------------------------------------------------------------------------
__global__ __launch_bounds__(256) void rope_reshape(
    const u16* __restrict__ qkv, const float* __restrict__ cosp,
    const float* __restrict__ sinp, u16* __restrict__ Q, u16* __restrict__ Kb)
{
    const size_t QN = (size_t)M_TOK * NH_ * 64;
    size_t id = (size_t)blockIdx.x * 256 + threadIdx.x;
    if (id < QN) {
        int j = id & 63; int h = (id >> 6) & (NH_ - 1); int tok = (int)(id >> 11);
        int b = tok >> 11, s = tok & (S_ - 1);
        float c  = cosp[(size_t)tok * HD_ + j];
        float sn = sinp[(size_t)tok * HD_ + j];
        float x1 = bf2f(qkv[(size_t)tok * NQKV + h * HD_ + j]);
        float x2 = bf2f(qkv[(size_t)tok * NQKV + h * HD_ + 64 + j]);
        size_t o = ((size_t)(b * NH_ + h) * S_ + s) * HD_ + j;
        Q[o]      = f2bf(x1 * c - x2 * sn);
        Q[o + 64] = f2bf(x2 * c + x1 * sn);
    } else {
        size_t kid = id - QN;
        int j = kid & 63; int h = (kid >> 6) & (NKV_ - 1); int tok = (int)(kid >> 9);
        int b = tok >> 11, s = tok & (S_ - 1);
        float c  = cosp[(size_t)tok * HD_ + j];
        float sn = sinp[(size_t)tok * HD_ + j];
        float x1 = bf2f(qkv[(size_t)tok * NQKV + 4096 + h * HD_ + j]);
        float x2 = bf2f(qkv[(size_t)tok * NQKV + 4096 + h * HD_ + 64 + j]);
        size_t o = ((size_t)(b * NKV_ + h) * S_ + s) * HD_ + j;
        Kb[o]      = f2bf(x1 * c - x2 * sn);
        Kb[o + 64] = f2bf(x2 * c + x1 * sn);
    }
}

// ---------------------------------------------------------------------------
// V transpose (unchanged): qkv V part -> Vt[b,hk,d,s]
// ---------------------------------------------------------------------------
__global__ __launch_bounds__(256) void v_transpose(
    const u16* __restrict__ qkv, u16* __restrict__ Vt)
{
    __shared__ __align__(16) u16 T[128][136];
    int bidx = blockIdx.x;
    int st = bidx & 15; int h = (bidx >> 4) & 7; int b = bidx >> 7;
    int s0 = st * 128;
    int tid = threadIdx.x;
    #pragma unroll
    for (int i = 0; i < 8; ++i) {
        int row = i * 16 + (tid >> 4); int cg = tid & 15;
        const u16* src = qkv + (size_t)(b * S_ + s0 + row) * NQKV + 5120 + h * HD_ + cg * 8;
        *(short8*)&T[row][cg * 8] = *(const short8*)src;
    }
    __syncthreads();
    #pragma unroll
    for (int i = 0; i < 8; ++i) {
        int d = i * 16 + (tid >> 4); int cg = tid & 15;
        __align__(16) u16 tmp[8];
        #pragma unroll
        for (int j = 0; j < 8; ++j) tmp[j] = T[cg * 8 + j][d];
        *(short8*)(Vt + ((size_t)(b * NKV_ + h) * HD_ + d) * S_ + s0 + cg * 8) =
            *(short8*)tmp;
    }
}

// ---------------------------------------------------------------------------
// Flash attention v4 (unchanged from round 5; verified).
// ---------------------------------------------------------------------------
__global__ __launch_bounds__(256) void flash_attn(
    const u16* __restrict__ Q, const u16* __restrict__ Kb,
    const u16* __restrict__ Vt, u16* __restrict__ AO)
{
    __shared__ __align__(16) u16 smem[2][8192];   // [buf][K 8KB | V 8KB]

    const int tid  = threadIdx.x;
    const int wave = tid >> 6, lane = tid & 63;
    const int l31 = lane & 31, hi = lane >> 5;

    const int i    = blockIdx.x;
    const int xcd  = i & 7;
    const int slot = i >> 3;
    const int g    = slot & 3;
    const int qb   = 15 - ((slot >> 2) & 15);   // longest blocks first
    const int b    = slot >> 6;
    const int hk   = xcd;
    const int h    = hk * 4 + g;
    const int qt   = qb * 4 + wave;             // this wave's q-tile
    const int q0   = qt * 32;
    const int qpos = q0 + l31;
    const int TB   = qb * 4 + 4;                // tiles processed per block

    const u16* Kbase = Kb + (size_t)(b * NKV_ + hk) * S_ * HD_;
    const u16* Vbase = Vt + (size_t)(b * NKV_ + hk) * HD_ * S_;

    // Q fragments (global, once); drain before manual vmcnt accounting
    const u16* Qp = Q + ((size_t)(b * NH_ + h) * S_ + q0 + l31) * HD_ + hi * 8;
    short8 qf[8];
    #pragma unroll
    for (int c = 0; c < 8; ++c) qf[c] = *(const short8*)(Qp + c * 16);
    __builtin_amdgcn_sched_barrier(0);
    asm volatile("s_waitcnt vmcnt(0)" ::: "memory");
    __builtin_amdgcn_sched_barrier(0);

    // staging: granule g16 in [0,512) per region, dest lane-linear.
    //   K: g16 = dslot*32 + kv  -> src col dslot*8 of row (kb+kv)
    //   V: g16 = kvslot*128 + d -> src col kb+kvslot*8 of row d
    const int gk0 = tid, gk1 = tid + 256;
    const int kdsl0 = gk0 >> 5, kkv0 = gk0 & 31;
    const int kdsl1 = gk1 >> 5, kkv1 = gk1 & 31;
    const int vks0 = gk0 >> 7, vd0 = gk0 & 127;
    const int vks1 = gk1 >> 7, vd1 = gk1 & 127;

    #define STAGE_KV(kb_, buf_)                                                        \
        do {                                                                           \
            u16* Ksd = &smem[buf_][0];                                                 \
            u16* Vsd = &smem[buf_][4096];                                              \
            __builtin_amdgcn_global_load_lds(                                          \
                GP(Kbase + (size_t)((kb_) + kkv0) * HD_ + kdsl0 * 8),                  \
                LP(Ksd + gk0 * 8), 16, 0, 0);                                          \
            __builtin_amdgcn_global_load_lds(                                          \
                GP(Kbase + (size_t)((kb_) + kkv1) * HD_ + kdsl1 * 8),                  \
                LP(Ksd + gk1 * 8), 16, 0, 0);                                          \
            __builtin_amdgcn_global_load_lds(                                          \
                GP(Vbase + (size_t)vd0 * S_ + (kb_) + vks0 * 8),                       \
                LP(Vsd + gk0 * 8), 16, 0, 0);                                          \
            __builtin_amdgcn_global_load_lds(                                          \
                GP(Vbase + (size_t)vd1 * S_ + (kb_) + vks1 * 8),                       \
                LP(Vsd + gk1 * 8), 16, 0, 0);                                          \
        } while (0)

    float m = -1e30f, l = 0.f;
    floatx16 o[4];
    #pragma unroll
    for (int n = 0; n < 4; ++n)
        #pragma unroll
        for (int r = 0; r < 16; ++r) o[n][r] = 0.f;

    // prologue: stage tiles 0 and 1 (TB >= 4 always)
    STAGE_KV(0, 0);
    STAGE_KV(32, 1);
    __builtin_amdgcn_sched_barrier(0);
    asm volatile("s_waitcnt vmcnt(4)" ::: "memory");
    __builtin_amdgcn_sched_barrier(0);
    __builtin_amdgcn_s_barrier();

    #pragma unroll 1
    for (int t = 0; t < TB; ++t) {
        const u16* Ks = &smem[t & 1][0];
        const u16* Vs = &smem[t & 1][4096];

        if (t <= qt) {
            const int kb = t * 32;

            // S^T[kv][q]: K from LDS (granule (2c+hi)*32 + l31), 2 acc chains
            floatx16 ca, cb;
            #pragma unroll
            for (int r = 0; r < 16; ++r) { ca[r] = 0.f; cb[r] = 0.f; }
            __builtin_amdgcn_s_setprio(1);
            #pragma unroll
            for (int c = 0; c < 8; c += 2) {
                ca = __builtin_amdgcn_mfma_f32_32x32x16_bf16(
                    *(const short8*)(Ks + (2 * c + hi) * 256 + l31 * 8),
                    qf[c], ca, 0, 0, 0);
                cb = __builtin_amdgcn_mfma_f32_32x32x16_bf16(
                    *(const short8*)(Ks + (2 * (c + 1) + hi) * 256 + l31 * 8),
                    qf[c + 1], cb, 0, 0, 0);
            }
            __builtin_amdgcn_s_setprio(0);

            float s[16];
            #pragma unroll
            for (int r = 0; r < 16; ++r) s[r] = ca[r] + cb[r];

            if (t == qt) {             // diagonal tile: causal mask
                #pragma unroll
                for (int r = 0; r < 16; ++r) {
                    const int kvr = (r & 3) + 8 * (r >> 2) + 4 * hi;
                    if (kb + kvr > qpos) s[r] = -1e38f;
                }
            }

            float b0 = fmaxf(fmaxf(s[0], s[1]), fmaxf(s[2], s[3]));
            float b1 = fmaxf(fmaxf(s[4], s[5]), fmaxf(s[6], s[7]));
            float b2 = fmaxf(fmaxf(s[8], s[9]), fmaxf(s[10], s[11]));
            float b3 = fmaxf(fmaxf(s[12], s[13]), fmaxf(s[14], s[15]));
            float bm = fmaxf(fmaxf(b0, b1), fmaxf(b2, b3));
            bm = fmaxf(bm, __shfl_xor(bm, 32));
            const float bmS = bm * SCALE;

            if (__any(bmS > m)) {      // rescale only when a max grew (exact)
                const float mn = fmaxf(m, bmS);
                const float al = __expf(m - mn);
                m = mn;
                l *= al;
                #pragma unroll
                for (int n = 0; n < 4; ++n)
                    #pragma unroll
                    for (int r = 0; r < 16; ++r) o[n][r] *= al;
            }

            float p[16];
            float rs = 0.f;
            #pragma unroll
            for (int r = 0; r < 16; ++r) {
                p[r] = __expf(fmaf(s[r], SCALE, -m));
                rs += p[r];
            }
            rs += __shfl_xor(rs, 32);
            l += rs;

            // P^T B-fragments: 8 cvt_pk + 4 xor-32 shuffles + selects
            u32 P01 = cvt_pk_bf16(p[0],  p[1]);
            u32 P23 = cvt_pk_bf16(p[2],  p[3]);
            u32 P45 = cvt_pk_bf16(p[4],  p[5]);
            u32 P67 = cvt_pk_bf16(p[6],  p[7]);
            u32 P89 = cvt_pk_bf16(p[8],  p[9]);
            u32 Pab = cvt_pk_bf16(p[10], p[11]);
            u32 Pcd = cvt_pk_bf16(p[12], p[13]);
            u32 Pef = cvt_pk_bf16(p[14], p[15]);
            u32 x1 = __shfl_xor(hi ? P01 : P45, 32);
            u32 x2 = __shfl_xor(hi ? P23 : P67, 32);
            u32 x3 = __shfl_xor(hi ? P89 : Pcd, 32);
            u32 x4 = __shfl_xor(hi ? Pab : Pef, 32);

            union { short8 v; u32 w[4]; } f0, f1;
            f0.w[0] = hi ? x1 : P01;  f0.w[1] = hi ? x2 : P23;
            f0.w[2] = hi ? P45 : x1;  f0.w[3] = hi ? P67 : x2;
            f1.w[0] = hi ? x3 : P89;  f1.w[1] = hi ? x4 : Pab;
            f1.w[2] = hi ? Pcd : x3;  f1.w[3] = hi ? Pef : x4;

            // O^T[d][q] += V^T[d][kv] * P^T[kv][q]; V from LDS
            __builtin_amdgcn_s_setprio(1);
            #pragma unroll
            for (int n = 0; n < 4; ++n) {
                o[n] = __builtin_amdgcn_mfma_f32_32x32x16_bf16(
                    *(const short8*)(Vs + (hi) * 1024 + (n * 32 + l31) * 8),
                    f0.v, o[n], 0, 0, 0);
                o[n] = __builtin_amdgcn_mfma_f32_32x32x16_bf16(
                    *(const short8*)(Vs + (2 + hi) * 1024 + (n * 32 + l31) * 8),
                    f1.v, o[n], 0, 0, 0);
            }
            __builtin_amdgcn_s_setprio(0);
        }

        __builtin_amdgcn_s_barrier();          // all waves done with buf[t&1]
        __builtin_amdgcn_sched_barrier(0);
        if (t + 2 < TB) {
            STAGE_KV((t + 2) * 32, t & 1);     // refill just-freed buffer
            __builtin_amdgcn_sched_barrier(0);
            asm volatile("s_waitcnt vmcnt(4)" ::: "memory");   // t+1 resident
        } else if (t + 1 < TB) {
            asm volatile("s_waitcnt vmcnt(0)" ::: "memory");
        }
        __builtin_amdgcn_sched_barrier(0);
        __builtin_amdgcn_s_barrier();
    }
    #undef STAGE_KV

    // epilogue: lane holds O^T[d = n*32 + (r&3)+8*(r>>2)+4*hi][q = l31]
    const float inv = 1.0f / l;
    u16* dst = AO + ((size_t)(b * S_) + q0 + l31) * (NH_ * HD_) + h * HD_ + hi * 4;
    #pragma unroll
    for (int n = 0; n < 4; ++n)
        #pragma unroll
        for (int rg = 0; rg < 4; ++rg) {
            u32 lo  = cvt_pk_bf16(o[n][rg * 4 + 0] * inv, o[n][rg * 4 + 1] * inv);
            u32 hi2 = cvt_pk_bf16(o[n][rg * 4 + 2] * inv, o[n][rg * 4 + 3] * inv);
            *(uint2*)(dst + n * 32 + rg * 8) = make_uint2(lo, hi2);
        }
}

// ---------------------------------------------------------------------------
// Workspace layout (128 MiB total, stream-ordered reuse):
//   [0,48)    qkv_raw  -> AO (reuse [0,32)) after v_transpose
//   [48,96)   Wqkv bf16 (live only through QKV GEMM)
//             -> Qb [48,80), Kb [80,88), Vt [88,96)
//   [96,128)  hs bf16 (live through QKV GEMM) -> Wo bf16 (after flash)
// ---------------------------------------------------------------------------
extern "C" void kernel_launch(void* const* d_in, const int* in_sizes, int n_in,
                              void* d_out, int out_size, void* d_ws, size_t ws_size,
                              hipStream_t stream)
{
    const float* hs   = (const float*)d_in[0];
    const float* cosp = (const float*)d_in[1];
    const float* sinp = (const float*)d_in[2];
    const float* wq   = (const float*)d_in[3];
    const float* wk   = (const float*)d_in[4];
    const float* wv   = (const float*)d_in[5];
    const float* wo   = (const float*)d_in[6];
    float* out = (float*)d_out;
    char* ws = (char*)d_ws;

    const size_t MB = 1024 * 1024;
    u16* qkv_raw = (u16*)ws;                      // 48 MiB
    u16* AO      = (u16*)ws;                      // 32 MiB (reuse)
    u16* Wqkv    = (u16*)(ws + 48 * MB);          // 48 MiB (transient)
    u16* Qb      = (u16*)(ws + 48 * MB);          // 32 MiB (after QKV GEMM)
    u16* Kb      = (u16*)(ws + 80 * MB);          //  8 MiB
    u16* Vt      = (u16*)(ws + 88 * MB);          //  8 MiB
    u16* hs_bf   = (u16*)(ws + 96 * MB);          // 32 MiB
    u16* Wo_bf   = (u16*)(ws + 96 * MB);          // 32 MiB (after flash)

    cvt_bf16<<<8192, 256, 0, stream>>>(hs, hs_bf, (M_TOK * D_) / 8);
    cvt_bf16<<<8192, 256, 0, stream>>>(wq, Wqkv, (NH_ * HD_ * D_) / 8);
    cvt_bf16<<<2048, 256, 0, stream>>>(wk, Wqkv + (size_t)NH_ * HD_ * D_, (NKV_ * HD_ * D_) / 8);
    cvt_bf16<<<2048, 256, 0, stream>>>(wv, Wqkv + (size_t)(NH_ + NKV_) * HD_ * D_, (NKV_ * HD_ * D_) / 8);

    // QKV GEMM: M=4096, N=6144 -> grid 24x16 = 384 blocks
    gemm_pipe<false><<<dim3(NQKV / 256, M_TOK / 256), 512, 0, stream>>>(
        hs_bf, Wqkv, qkv_raw, M_TOK, NQKV, D_);

    rope_reshape<<<40960, 256, 0, stream>>>(qkv_raw, cosp, sinp, Qb, Kb);

    v_transpose<<<256, 256, 0, stream>>>(qkv_raw, Vt);

    flash_attn<<<1024, 256, 0, stream>>>(Qb, Kb, Vt, AO);

    cvt_bf16<<<8192, 256, 0, stream>>>(wo, Wo_bf, (D_ * NH_ * HD_) / 8);

    // WO GEMM: M=4096, N=4096 -> grid 16x16 = 256 blocks (exactly 1 round)
    gemm_pipe<true><<<dim3(D_ / 256, M_TOK / 256), 512, 0, stream>>>(
        AO, Wo_bf, out, M_TOK, D_, NH_ * HD_);
}